// Round 1
// baseline (433.867 us; speedup 1.0000x reference)
//
#include <hip/hip_runtime.h>
#include <hip/hip_bf16.h>

typedef unsigned short u16;
typedef __attribute__((ext_vector_type(8))) __bf16 bf16x8;
typedef __attribute__((ext_vector_type(4))) float f32x4;
typedef __attribute__((ext_vector_type(4))) unsigned short u16x4;

#define SCALE_QK 0.08838834764831845f

__device__ __forceinline__ u16 f2bf(float x) {
  union { float f; unsigned u; } v; v.f = x;
  unsigned r = v.u + 0x7fffu + ((v.u >> 16) & 1u);
  return (u16)(r >> 16);
}

__device__ __forceinline__ void gload_lds16(const u16* g, u16* l) {
  __builtin_amdgcn_global_load_lds(
      (const __attribute__((address_space(1))) unsigned*)g,
      (__attribute__((address_space(3))) unsigned*)l, 16, 0, 0);
}

// Generic C[M,N] = scale * (A[M,K] @ B[N,K]^T) (+ bias[n]) ; optional accumulate.
// A, B bf16 row-major; out f32 or bf16. Grid: (N/128, M/128, batch).
template<bool OUT_BF16, bool ACCUM, bool HAS_BIAS>
__global__ __launch_bounds__(256)
void gemm_bt(const u16* __restrict__ A, int lda, long sA,
             const u16* __restrict__ B, int ldb, long sB,
             void* __restrict__ Cv, int ldc, long sC,
             int K, float scale, const float* __restrict__ scale_ptr,
             const float* __restrict__ bias)
{
  __shared__ u16 As[128 * 64];
  __shared__ u16 Bs[128 * 64];
  const int bz   = blockIdx.z;
  const u16* Ap  = A + (long)bz * sA;
  const u16* Bp  = B + (long)bz * sB;
  const int tid  = threadIdx.x;
  const int wid  = tid >> 6;
  const int lane = tid & 63;
  const long m0  = (long)blockIdx.y * 128;
  const long n0  = (long)blockIdx.x * 128;
  const int lrow = lane >> 3;        // 0..7 row within 8-row chunk
  const int lk   = (lane & 7) << 3;  // 0,8,...,56 k-offset (8 bf16 = 16B)
  const int wr   = wid >> 1, wc = wid & 1;

  f32x4 acc[4][4];
#pragma unroll
  for (int i = 0; i < 4; ++i)
#pragma unroll
    for (int j = 0; j < 4; ++j) acc[i][j] = (f32x4){0.f, 0.f, 0.f, 0.f};

  for (int k0 = 0; k0 < K; k0 += 64) {
#pragma unroll
    for (int c4 = 0; c4 < 4; ++c4) {
      const int chunk = (wid << 2) + c4;          // 0..15, 8 rows each
      gload_lds16(Ap + (m0 + (chunk << 3) + lrow) * lda + k0 + lk, &As[chunk << 9]);
      gload_lds16(Bp + (n0 + (chunk << 3) + lrow) * ldb + k0 + lk, &Bs[chunk << 9]);
    }
    __syncthreads();
#pragma unroll
    for (int kk = 0; kk < 2; ++kk) {
      bf16x8 af[4], bfr[4];
      const int kof   = (kk << 5) + ((lane >> 4) << 3);
      const int rbase = lane & 15;
#pragma unroll
      for (int i = 0; i < 4; ++i)
        af[i] = *(const bf16x8*)&As[(((wr << 6) + (i << 4) + rbase) << 6) + kof];
#pragma unroll
      for (int j = 0; j < 4; ++j)
        bfr[j] = *(const bf16x8*)&Bs[(((wc << 6) + (j << 4) + rbase) << 6) + kof];
#pragma unroll
      for (int i = 0; i < 4; ++i)
#pragma unroll
        for (int j = 0; j < 4; ++j)
          acc[i][j] = __builtin_amdgcn_mfma_f32_16x16x32_bf16(af[i], bfr[j], acc[i][j], 0, 0, 0);
    }
    __syncthreads();
  }

  float sc = scale;
  if (scale_ptr) sc *= scale_ptr[0];
  const int r0 = (lane >> 4) << 2;
  const int cL = lane & 15;
#pragma unroll
  for (int i = 0; i < 4; ++i) {
#pragma unroll
    for (int j = 0; j < 4; ++j) {
      const long row = m0 + (wr << 6) + (i << 4) + r0;
      const long col = n0 + (wc << 6) + (j << 4) + cL;
      float bv = 0.f;
      if (HAS_BIAS) bv = bias[col];
      if (OUT_BF16) {
        u16* Cp = (u16*)Cv + (long)bz * sC;
#pragma unroll
        for (int r = 0; r < 4; ++r)
          Cp[(row + r) * ldc + col] = f2bf(acc[i][j][r] * sc + bv);
      } else {
        float* Cp = (float*)Cv + (long)bz * sC;
#pragma unroll
        for (int r = 0; r < 4; ++r) {
          float v = acc[i][j][r] * sc + bv;
          if (ACCUM) Cp[(row + r) * ldc + col] += v;
          else       Cp[(row + r) * ldc + col] = v;
        }
      }
    }
  }
}

// Row softmax over 2048 f32 -> bf16. One block (256 thr) per row.
__global__ __launch_bounds__(256)
void softmax_rows2048(const float* __restrict__ src, u16* __restrict__ dst) {
  const long row = blockIdx.x;
  const float4* s = (const float4*)(src + row * 2048);
  const int tid = threadIdx.x;
  float4 a = s[tid * 2], b = s[tid * 2 + 1];
  float m = fmaxf(fmaxf(fmaxf(a.x, a.y), fmaxf(a.z, a.w)),
                  fmaxf(fmaxf(b.x, b.y), fmaxf(b.z, b.w)));
#pragma unroll
  for (int o = 32; o > 0; o >>= 1) m = fmaxf(m, __shfl_xor(m, o));
  __shared__ float redm[4];
  __shared__ float reds[4];
  if ((tid & 63) == 0) redm[tid >> 6] = m;
  __syncthreads();
  m = fmaxf(fmaxf(redm[0], redm[1]), fmaxf(redm[2], redm[3]));
  float e[8];
  e[0] = __expf(a.x - m); e[1] = __expf(a.y - m); e[2] = __expf(a.z - m); e[3] = __expf(a.w - m);
  e[4] = __expf(b.x - m); e[5] = __expf(b.y - m); e[6] = __expf(b.z - m); e[7] = __expf(b.w - m);
  float sum = e[0] + e[1] + e[2] + e[3] + e[4] + e[5] + e[6] + e[7];
#pragma unroll
  for (int o = 32; o > 0; o >>= 1) sum += __shfl_xor(sum, o);
  if ((tid & 63) == 0) reds[tid >> 6] = sum;
  __syncthreads();
  sum = reds[0] + reds[1] + reds[2] + reds[3];
  const float inv = 1.f / sum;
  u16x4 o1 = { f2bf(e[0] * inv), f2bf(e[1] * inv), f2bf(e[2] * inv), f2bf(e[3] * inv) };
  u16x4 o2 = { f2bf(e[4] * inv), f2bf(e[5] * inv), f2bf(e[6] * inv), f2bf(e[7] * inv) };
  u16x4* d = (u16x4*)(dst + row * 2048);
  d[tid * 2]     = o1;
  d[tid * 2 + 1] = o2;
}

// dst[C,R] (bf16) = src[R,C] (f32). Grid (C/32, R/32), block (32,8).
__global__ void transpose_f32_to_bf16(const float* __restrict__ src, u16* __restrict__ dst,
                                      int R, int C) {
  __shared__ float t[32][33];
  const int c0 = blockIdx.x * 32, r0 = blockIdx.y * 32;
  const int tx = threadIdx.x, ty = threadIdx.y;
#pragma unroll
  for (int i = 0; i < 4; ++i)
    t[ty + i * 8][tx] = src[(long)(r0 + ty + i * 8) * C + c0 + tx];
  __syncthreads();
#pragma unroll
  for (int i = 0; i < 4; ++i)
    dst[(long)(c0 + ty + i * 8) * R + r0 + tx] = f2bf(t[tx][ty + i * 8]);
}

// dst[c][r] = src[r][c], bf16, strided+batched. Grid (C/32, R/32, batch), block (32,8).
__global__ void transpose_bf16_batched(const u16* __restrict__ src, int ss, long sbat,
                                       u16* __restrict__ dst, int ds, long dbat) {
  __shared__ u16 t[32][33];
  const u16* s = src + (long)blockIdx.z * sbat;
  u16* d = dst + (long)blockIdx.z * dbat;
  const int c0 = blockIdx.x * 32, r0 = blockIdx.y * 32;
  const int tx = threadIdx.x, ty = threadIdx.y;
#pragma unroll
  for (int i = 0; i < 4; ++i)
    t[ty + i * 8][tx] = s[(long)(r0 + ty + i * 8) * ss + c0 + tx];
  __syncthreads();
#pragma unroll
  for (int i = 0; i < 4; ++i)
    d[(long)(c0 + ty + i * 8) * ds + r0 + tx] = t[tx][ty + i * 8];
}

__global__ __launch_bounds__(256)
void convert_f32_to_bf16(const float* __restrict__ src, u16* __restrict__ dst, long n4) {
  long i = (long)blockIdx.x * 256 + threadIdx.x;
  if (i < n4) {
    float4 v = ((const float4*)src)[i];
    *(u16x4*)(dst + i * 4) = (u16x4){ f2bf(v.x), f2bf(v.y), f2bf(v.z), f2bf(v.w) };
  }
}

__global__ __launch_bounds__(256)
void cam_tanh_kernel(const float* __restrict__ ctx, const float* __restrict__ gate,
                     u16* __restrict__ out, int n) {
  int i = blockIdx.x * 256 + threadIdx.x;
  if (i < n) {
    int d = i & 127;
    out[i] = f2bf(tanhf(ctx[i] * gate[d]));
  }
}

__global__ void calc_lw_kernel(const float* w0, const float* w1, float* lw) {
  *lw = 1.f / (1.f + __expf(-(w0[0] + 0.5f * w1[0])));
}

extern "C" void kernel_launch(void* const* d_in, const int* in_sizes, int n_in,
                              void* d_out, int out_size, void* d_ws, size_t ws_size,
                              hipStream_t stream) {
  const float* hs       = (const float*)d_in[0];
  const float* c_attn_w = (const float*)d_in[1];
  const float* c_attn_b = (const float*)d_in[2];
  const float* c_proj_w = (const float*)d_in[3];
  const float* c_proj_b = (const float*)d_in[4];
  const float* cam_gate = (const float*)d_in[5];
  const float* cam_w0   = (const float*)d_in[6];
  const float* cam_w1   = (const float*)d_in[7];
  float* out = (float*)d_out;

  char* w = (char*)d_ws;
  float* lw      = (float*)(w + 0);
  u16*   hs_b    = (u16*)(w + 256);                  // 16 MB (reused as baseA)
  u16*   waT_b   = (u16*)(w + 256 + 16777216UL);     // 24 MB
  u16*   wpT_b   = (u16*)(w + 256 + 41943040UL);     // 8 MB
  u16*   qkv_b   = (u16*)(w + 256 + 50331648UL);     // 48 MB
  u16*   vT_b    = (u16*)(w + 256 + 100663296UL);    // 16 MB
  float* scoresF = (float*)(w + 256 + 117440512UL);  // 32 MB (reused as ctxE bf16)
  float* camS    = (float*)(w + 256 + 150994944UL);  // 32 MB (reused as P bf16)
  float* ctxF    = (float*)(w + 256 + 184549376UL);  // 2 MB
  u16*   camT_b  = (u16*)(w + 256 + 186646528UL);    // 1 MB
  u16* baseA_b = hs_b;
  u16* P_b     = (u16*)camS;
  u16* ctxE_b  = (u16*)scoresF;

  dim3 b256(256);

  calc_lw_kernel<<<dim3(1), dim3(1), 0, stream>>>(cam_w0, cam_w1, lw);
  convert_f32_to_bf16<<<dim3(8192), b256, 0, stream>>>(hs, hs_b, 2097152L);
  transpose_f32_to_bf16<<<dim3(192, 64), dim3(32, 8), 0, stream>>>(c_attn_w, waT_b, 2048, 6144);
  transpose_f32_to_bf16<<<dim3(64, 64), dim3(32, 8), 0, stream>>>(c_proj_w, wpT_b, 2048, 2048);

  // GEMM1: qkv (4096x6144 bf16) = hs @ W_attn + b
  gemm_bt<true, false, true><<<dim3(48, 32, 1), b256, 0, stream>>>(
      hs_b, 2048, 0L, waT_b, 2048, 0L, qkv_b, 6144, 0L,
      2048, 1.f, nullptr, c_attn_b);

  // V^T per batch (2048x2048 each)
  transpose_bf16_batched<<<dim3(64, 64, 2), dim3(32, 8), 0, stream>>>(
      qkv_b + 4096, 6144, 2048L * 6144, vT_b, 2048, 2048L * 2048);

  // GEMM2: scores = Q @ K^T * SCALE (f32)
  gemm_bt<false, false, false><<<dim3(16, 16, 2), b256, 0, stream>>>(
      qkv_b, 6144, 2048L * 6144, qkv_b + 2048, 6144, 2048L * 6144,
      scoresF, 2048, 2048L * 2048, 2048, SCALE_QK, nullptr, nullptr);

  // GEMM3: camS = Q_cam @ K_cam^T * SCALE (K=128, f32)
  gemm_bt<false, false, false><<<dim3(16, 16, 2), b256, 0, stream>>>(
      qkv_b, 6144, 2048L * 6144, qkv_b + 2048, 6144, 2048L * 6144,
      camS, 2048, 2048L * 2048, 128, SCALE_QK, nullptr, nullptr);

  // base_A = softmax(camS) -> bf16
  softmax_rows2048<<<dim3(4096), b256, 0, stream>>>(camS, baseA_b);

  // GEMM4: cam_ctx (2048x128 f32 per batch) = base_A @ V_cam
  gemm_bt<false, false, false><<<dim3(1, 16, 2), b256, 0, stream>>>(
      baseA_b, 2048, 2048L * 2048, vT_b, 2048, 2048L * 2048,
      ctxF, 128, 2048L * 128, 2048, 1.f, nullptr, nullptr);

  // camT = tanh(cam_ctx * gate) -> bf16
  cam_tanh_kernel<<<dim3(2048), b256, 0, stream>>>(ctxF, cam_gate, camT_b, 524288);

  // GEMM5: scores += camT @ K_cam^T * (SCALE * layer_weight)   (K=128, accumulate)
  gemm_bt<false, true, false><<<dim3(16, 16, 2), b256, 0, stream>>>(
      camT_b, 128, 2048L * 128, qkv_b + 2048, 6144, 2048L * 6144,
      scoresF, 2048, 2048L * 2048, 128, SCALE_QK, lw, nullptr);

  // P = softmax(scores) -> bf16
  softmax_rows2048<<<dim3(4096), b256, 0, stream>>>(scoresF, P_b);

  // GEMM6: context (bf16) = P @ V
  gemm_bt<true, false, false><<<dim3(16, 16, 2), b256, 0, stream>>>(
      P_b, 2048, 2048L * 2048, vT_b, 2048, 2048L * 2048,
      ctxE_b, 2048, 2048L * 2048, 2048, 1.f, nullptr, nullptr);

  // GEMM7: out (f32) = context @ W_proj + b
  gemm_bt<false, false, true><<<dim3(16, 32, 1), b256, 0, stream>>>(
      ctxE_b, 2048, 0L, wpT_b, 2048, 0L, out, 2048, 0L,
      2048, 1.f, nullptr, c_proj_b);
}

// Round 2
// 399.762 us; speedup vs baseline: 1.0853x; 1.0853x over previous
//
#include <hip/hip_runtime.h>
#include <hip/hip_bf16.h>

typedef unsigned short u16;
typedef __attribute__((ext_vector_type(8))) __bf16 bf16x8;
typedef __attribute__((ext_vector_type(4))) float f32x4;
typedef __attribute__((ext_vector_type(4))) unsigned short u16x4;

#define SCALE_QK 0.08838834764831845f

__device__ __forceinline__ u16 f2bf(float x) {
  union { float f; unsigned u; } v; v.f = x;
  unsigned r = v.u + 0x7fffu + ((v.u >> 16) & 1u);
  return (u16)(r >> 16);
}

__device__ __forceinline__ void gload_lds16(const u16* g, u16* l) {
  __builtin_amdgcn_global_load_lds(
      (const __attribute__((address_space(1))) unsigned*)g,
      (__attribute__((address_space(3))) unsigned*)l, 16, 0, 0);
}

__device__ __forceinline__ void wgbar() {
  asm volatile("" ::: "memory");
  __builtin_amdgcn_s_barrier();
  asm volatile("" ::: "memory");
}

// ---------------------------------------------------------------------------
// 256x256 tile, BK=32, 4-deep LDS pipeline, 8 waves (2M x 4N), 512 threads.
// A[M,K], B[N,K] bf16 row-major; C = scale*(A@B^T)(+bias). Requires M,N %256==0,
// K%32==0, K>=96. LDS: 4 bufs x (A 256x32 + B 256x32) bf16 = 131072 B (dynamic).
// Swizzle: element col ^= ((row>>1)&3)<<3, applied on global SOURCE (staging)
// and on ds_read address (global_load_lds dest must stay linear).
// ---------------------------------------------------------------------------
template<bool OUT_BF16, bool HAS_BIAS>
__global__ __launch_bounds__(512, 2)
void gemm256(const u16* __restrict__ A, int lda, long sA,
             const u16* __restrict__ B, int ldb, long sB,
             void* __restrict__ Cv, int ldc, long sC,
             int K, float scale, const float* __restrict__ scale_ptr,
             const float* __restrict__ bias, int nbx)
{
  extern __shared__ u16 lds[];
  const int bz = blockIdx.z;
  const u16* Ap = A + (long)bz * sA;
  const u16* Bp = B + (long)bz * sB;

  // bijective XCD swizzle (m204)
  const int nwg = gridDim.x;
  const int orig = blockIdx.x;
  const int q = nwg >> 3, rr = nwg & 7;
  const int xcd = orig & 7, lp = orig >> 3;
  const int wg = (xcd < rr ? xcd * (q + 1) : rr * (q + 1) + (xcd - rr) * q) + lp;
  const int bx = wg % nbx, by = wg / nbx;
  const long m0 = (long)by * 256, n0 = (long)bx * 256;

  const int tid = threadIdx.x;
  const int wid = tid >> 6, lane = tid & 63;
  const int wm = wid >> 2, wn = wid & 3;   // wave tile: rows wm*128, cols wn*64
  const int rl = lane & 15, g = lane >> 4;

  // fragment LDS element-offsets (swizzled read side)
  int offA[8], offB[4];
#pragma unroll
  for (int i = 0; i < 8; ++i) {
    const int row = wm * 128 + i * 16 + rl;
    offA[i] = row * 32 + ((g ^ ((row >> 1) & 3)) << 3);
  }
#pragma unroll
  for (int j = 0; j < 4; ++j) {
    const int row = wn * 64 + j * 16 + rl;
    offB[j] = row * 32 + ((g ^ ((row >> 1) & 3)) << 3);
  }

  // staging: per thread 16B; l=0 covers rows 0-127, l=1 rows 128-255.
  // global source col pre-swizzled (inverse == same XOR, involution).
  const int rA = tid >> 2;                                   // 0..127
  const int colsw = (((lane & 3) ^ ((rA >> 1) & 3)) << 3);   // key same for rA+128
  const u16* srcA0 = Ap + (m0 + rA) * (long)lda + colsw;
  const u16* srcA1 = Ap + (m0 + rA + 128) * (long)lda + colsw;
  const u16* srcB0 = Bp + (n0 + rA) * (long)ldb + colsw;
  const u16* srcB1 = Bp + (n0 + rA + 128) * (long)ldb + colsw;
  const int dL0 = wid * 512, dL1 = wid * 512 + 4096;         // wave-uniform LDS dests

  const int NT = K >> 5;   // assumes NT >= 3

  // prologue: stage tiles 0,1,2 (12 loads in flight / thread)
#pragma unroll 1
  for (int t = 0; t < 3; ++t) {
    u16* bufp = lds + (t & 3) * 16384;
    gload_lds16(srcA0 + t * 32, bufp + dL0);
    gload_lds16(srcA1 + t * 32, bufp + dL1);
    gload_lds16(srcB0 + t * 32, bufp + 8192 + dL0);
    gload_lds16(srcB1 + t * 32, bufp + 8192 + dL1);
  }

  f32x4 acc[8][4];
#pragma unroll
  for (int i = 0; i < 8; ++i)
#pragma unroll
    for (int j = 0; j < 4; ++j) acc[i][j] = (f32x4){0.f, 0.f, 0.f, 0.f};

#pragma unroll 1
  for (int t = 0; t < NT; ++t) {
    const u16* bA = lds + (t & 3) * 16384;
    const u16* bB = bA + 8192;
    const int pre = t + 3;
    const bool doPre = pre < NT;
    u16* pP = lds + (pre & 3) * 16384;
    const int rem = NT - 1 - t;
    // counted vmcnt: leave newer tiles' loads in flight (T4)
    if (rem >= 2)      asm volatile("s_waitcnt vmcnt(8)" ::: "memory");
    else if (rem == 1) asm volatile("s_waitcnt vmcnt(4)" ::: "memory");
    else               asm volatile("s_waitcnt vmcnt(0)" ::: "memory");
    wgbar();           // tile t fully staged for all waves

    bf16x8 av[4], bv_[4];
#pragma unroll
    for (int i = 0; i < 4; ++i) av[i] = *(const bf16x8*)(bA + offA[i]);
#pragma unroll
    for (int j = 0; j < 4; ++j) bv_[j] = *(const bf16x8*)(bB + offB[j]);
    if (doPre) {       // stage A-half of tile t+3 (overwrites fully-read t-1 buf)
      gload_lds16(srcA0 + pre * 32, pP + dL0);
      gload_lds16(srcA1 + pre * 32, pP + dL1);
    }
    wgbar();
    __builtin_amdgcn_s_setprio(1);
#pragma unroll
    for (int i = 0; i < 4; ++i)
#pragma unroll
      for (int j = 0; j < 4; ++j)
        acc[i][j] = __builtin_amdgcn_mfma_f32_16x16x32_bf16(av[i], bv_[j], acc[i][j], 0, 0, 0);
    __builtin_amdgcn_s_setprio(0);

#pragma unroll
    for (int i = 0; i < 4; ++i) av[i] = *(const bf16x8*)(bA + offA[i + 4]);
    if (doPre) {       // stage B-half of tile t+3
      gload_lds16(srcB0 + pre * 32, pP + 8192 + dL0);
      gload_lds16(srcB1 + pre * 32, pP + 8192 + dL1);
    }
    wgbar();
    __builtin_amdgcn_s_setprio(1);
#pragma unroll
    for (int i = 0; i < 4; ++i)
#pragma unroll
      for (int j = 0; j < 4; ++j)
        acc[i + 4][j] = __builtin_amdgcn_mfma_f32_16x16x32_bf16(av[i], bv_[j], acc[i + 4][j], 0, 0, 0);
    __builtin_amdgcn_s_setprio(0);
  }

  float sc = scale;
  if (scale_ptr) sc *= scale_ptr[0];
  const int r0 = (lane >> 4) << 2;
  const int cL = lane & 15;
#pragma unroll
  for (int i = 0; i < 8; ++i) {
#pragma unroll
    for (int j = 0; j < 4; ++j) {
      const long row = m0 + wm * 128 + i * 16 + r0;
      const long col = n0 + wn * 64 + j * 16 + cL;
      float bvs = 0.f;
      if (HAS_BIAS) bvs = bias[col];
      if (OUT_BF16) {
        u16* Cp = (u16*)Cv + (long)bz * sC;
#pragma unroll
        for (int r = 0; r < 4; ++r)
          Cp[(row + r) * ldc + col] = f2bf(acc[i][j][r] * sc + bvs);
      } else {
        float* Cp = (float*)Cv + (long)bz * sC;
#pragma unroll
        for (int r = 0; r < 4; ++r)
          Cp[(row + r) * ldc + col] = acc[i][j][r] * sc + bvs;
      }
    }
  }
}

// ---------------------------------------------------------------------------
// Legacy 128x128 kernel (validated) for the remaining GEMMs.
// ---------------------------------------------------------------------------
template<bool OUT_BF16, bool ACCUM, bool HAS_BIAS>
__global__ __launch_bounds__(256)
void gemm_bt(const u16* __restrict__ A, int lda, long sA,
             const u16* __restrict__ B, int ldb, long sB,
             void* __restrict__ Cv, int ldc, long sC,
             int K, float scale, const float* __restrict__ scale_ptr,
             const float* __restrict__ bias)
{
  __shared__ u16 As[128 * 64];
  __shared__ u16 Bs[128 * 64];
  const int bz   = blockIdx.z;
  const u16* Ap  = A + (long)bz * sA;
  const u16* Bp  = B + (long)bz * sB;
  const int tid  = threadIdx.x;
  const int wid  = tid >> 6;
  const int lane = tid & 63;
  const long m0  = (long)blockIdx.y * 128;
  const long n0  = (long)blockIdx.x * 128;
  const int lrow = lane >> 3;
  const int lk   = (lane & 7) << 3;
  const int wr   = wid >> 1, wc = wid & 1;

  f32x4 acc[4][4];
#pragma unroll
  for (int i = 0; i < 4; ++i)
#pragma unroll
    for (int j = 0; j < 4; ++j) acc[i][j] = (f32x4){0.f, 0.f, 0.f, 0.f};

  for (int k0 = 0; k0 < K; k0 += 64) {
#pragma unroll
    for (int c4 = 0; c4 < 4; ++c4) {
      const int chunk = (wid << 2) + c4;
      gload_lds16(Ap + (m0 + (chunk << 3) + lrow) * lda + k0 + lk, &As[chunk << 9]);
      gload_lds16(Bp + (n0 + (chunk << 3) + lrow) * ldb + k0 + lk, &Bs[chunk << 9]);
    }
    __syncthreads();
#pragma unroll
    for (int kk = 0; kk < 2; ++kk) {
      bf16x8 af[4], bfr[4];
      const int kof   = (kk << 5) + ((lane >> 4) << 3);
      const int rbase = lane & 15;
#pragma unroll
      for (int i = 0; i < 4; ++i)
        af[i] = *(const bf16x8*)&As[(((wr << 6) + (i << 4) + rbase) << 6) + kof];
#pragma unroll
      for (int j = 0; j < 4; ++j)
        bfr[j] = *(const bf16x8*)&Bs[(((wc << 6) + (j << 4) + rbase) << 6) + kof];
#pragma unroll
      for (int i = 0; i < 4; ++i)
#pragma unroll
        for (int j = 0; j < 4; ++j)
          acc[i][j] = __builtin_amdgcn_mfma_f32_16x16x32_bf16(af[i], bfr[j], acc[i][j], 0, 0, 0);
    }
    __syncthreads();
  }

  float sc = scale;
  if (scale_ptr) sc *= scale_ptr[0];
  const int r0 = (lane >> 4) << 2;
  const int cL = lane & 15;
#pragma unroll
  for (int i = 0; i < 4; ++i) {
#pragma unroll
    for (int j = 0; j < 4; ++j) {
      const long row = m0 + (wr << 6) + (i << 4) + r0;
      const long col = n0 + (wc << 6) + (j << 4) + cL;
      float bv = 0.f;
      if (HAS_BIAS) bv = bias[col];
      if (OUT_BF16) {
        u16* Cp = (u16*)Cv + (long)bz * sC;
#pragma unroll
        for (int r = 0; r < 4; ++r)
          Cp[(row + r) * ldc + col] = f2bf(acc[i][j][r] * sc + bv);
      } else {
        float* Cp = (float*)Cv + (long)bz * sC;
#pragma unroll
        for (int r = 0; r < 4; ++r) {
          float v = acc[i][j][r] * sc + bv;
          if (ACCUM) Cp[(row + r) * ldc + col] += v;
          else       Cp[(row + r) * ldc + col] = v;
        }
      }
    }
  }
}

// Split-K (x8) variant for skinny GEMM4: atomicAdd f32 epilogue.
__global__ __launch_bounds__(256)
void gemm_bt_splitk(const u16* __restrict__ A, int lda, long sA,
                    const u16* __restrict__ B, int ldb, long sB,
                    float* __restrict__ C, int ldc, long sC,
                    int Kslice, float scale)
{
  __shared__ u16 As[128 * 64];
  __shared__ u16 Bs[128 * 64];
  const int ks = blockIdx.z & 7;
  const int bz = blockIdx.z >> 3;
  const u16* Ap  = A + (long)bz * sA + ks * Kslice;
  const u16* Bp  = B + (long)bz * sB + ks * Kslice;
  const int tid  = threadIdx.x;
  const int wid  = tid >> 6;
  const int lane = tid & 63;
  const long m0  = (long)blockIdx.y * 128;
  const long n0  = (long)blockIdx.x * 128;
  const int lrow = lane >> 3;
  const int lk   = (lane & 7) << 3;
  const int wr   = wid >> 1, wc = wid & 1;

  f32x4 acc[4][4];
#pragma unroll
  for (int i = 0; i < 4; ++i)
#pragma unroll
    for (int j = 0; j < 4; ++j) acc[i][j] = (f32x4){0.f, 0.f, 0.f, 0.f};

  for (int k0 = 0; k0 < Kslice; k0 += 64) {
#pragma unroll
    for (int c4 = 0; c4 < 4; ++c4) {
      const int chunk = (wid << 2) + c4;
      gload_lds16(Ap + (m0 + (chunk << 3) + lrow) * lda + k0 + lk, &As[chunk << 9]);
      gload_lds16(Bp + (n0 + (chunk << 3) + lrow) * ldb + k0 + lk, &Bs[chunk << 9]);
    }
    __syncthreads();
#pragma unroll
    for (int kk = 0; kk < 2; ++kk) {
      bf16x8 af[4], bfr[4];
      const int kof   = (kk << 5) + ((lane >> 4) << 3);
      const int rbase = lane & 15;
#pragma unroll
      for (int i = 0; i < 4; ++i)
        af[i] = *(const bf16x8*)&As[(((wr << 6) + (i << 4) + rbase) << 6) + kof];
#pragma unroll
      for (int j = 0; j < 4; ++j)
        bfr[j] = *(const bf16x8*)&Bs[(((wc << 6) + (j << 4) + rbase) << 6) + kof];
#pragma unroll
      for (int i = 0; i < 4; ++i)
#pragma unroll
        for (int j = 0; j < 4; ++j)
          acc[i][j] = __builtin_amdgcn_mfma_f32_16x16x32_bf16(af[i], bfr[j], acc[i][j], 0, 0, 0);
    }
    __syncthreads();
  }

  const int r0 = (lane >> 4) << 2;
  const int cL = lane & 15;
  float* Cp = C + (long)bz * sC;
#pragma unroll
  for (int i = 0; i < 4; ++i) {
#pragma unroll
    for (int j = 0; j < 4; ++j) {
      const long row = m0 + (wr << 6) + (i << 4) + r0;
      const long col = n0 + (wc << 6) + (j << 4) + cL;
#pragma unroll
      for (int r = 0; r < 4; ++r)
        atomicAdd(&Cp[(row + r) * ldc + col], acc[i][j][r] * scale);
    }
  }
}

// Row softmax over 2048 f32 -> bf16. One block (256 thr) per row.
__global__ __launch_bounds__(256)
void softmax_rows2048(const float* __restrict__ src, u16* __restrict__ dst) {
  const long row = blockIdx.x;
  const float4* s = (const float4*)(src + row * 2048);
  const int tid = threadIdx.x;
  float4 a = s[tid * 2], b = s[tid * 2 + 1];
  float m = fmaxf(fmaxf(fmaxf(a.x, a.y), fmaxf(a.z, a.w)),
                  fmaxf(fmaxf(b.x, b.y), fmaxf(b.z, b.w)));
#pragma unroll
  for (int o = 32; o > 0; o >>= 1) m = fmaxf(m, __shfl_xor(m, o));
  __shared__ float redm[4];
  __shared__ float reds[4];
  if ((tid & 63) == 0) redm[tid >> 6] = m;
  __syncthreads();
  m = fmaxf(fmaxf(redm[0], redm[1]), fmaxf(redm[2], redm[3]));
  float e[8];
  e[0] = __expf(a.x - m); e[1] = __expf(a.y - m); e[2] = __expf(a.z - m); e[3] = __expf(a.w - m);
  e[4] = __expf(b.x - m); e[5] = __expf(b.y - m); e[6] = __expf(b.z - m); e[7] = __expf(b.w - m);
  float sum = e[0] + e[1] + e[2] + e[3] + e[4] + e[5] + e[6] + e[7];
#pragma unroll
  for (int o = 32; o > 0; o >>= 1) sum += __shfl_xor(sum, o);
  if ((tid & 63) == 0) reds[tid >> 6] = sum;
  __syncthreads();
  sum = reds[0] + reds[1] + reds[2] + reds[3];
  const float inv = 1.f / sum;
  u16x4 o1 = { f2bf(e[0] * inv), f2bf(e[1] * inv), f2bf(e[2] * inv), f2bf(e[3] * inv) };
  u16x4 o2 = { f2bf(e[4] * inv), f2bf(e[5] * inv), f2bf(e[6] * inv), f2bf(e[7] * inv) };
  u16x4* d = (u16x4*)(dst + row * 2048);
  d[tid * 2]     = o1;
  d[tid * 2 + 1] = o2;
}

__global__ void transpose_f32_to_bf16(const float* __restrict__ src, u16* __restrict__ dst,
                                      int R, int C) {
  __shared__ float t[32][33];
  const int c0 = blockIdx.x * 32, r0 = blockIdx.y * 32;
  const int tx = threadIdx.x, ty = threadIdx.y;
#pragma unroll
  for (int i = 0; i < 4; ++i)
    t[ty + i * 8][tx] = src[(long)(r0 + ty + i * 8) * C + c0 + tx];
  __syncthreads();
#pragma unroll
  for (int i = 0; i < 4; ++i)
    dst[(long)(c0 + ty + i * 8) * R + r0 + tx] = f2bf(t[tx][ty + i * 8]);
}

__global__ void transpose_bf16_batched(const u16* __restrict__ src, int ss, long sbat,
                                       u16* __restrict__ dst, int ds, long dbat) {
  __shared__ u16 t[32][33];
  const u16* s = src + (long)blockIdx.z * sbat;
  u16* d = dst + (long)blockIdx.z * dbat;
  const int c0 = blockIdx.x * 32, r0 = blockIdx.y * 32;
  const int tx = threadIdx.x, ty = threadIdx.y;
#pragma unroll
  for (int i = 0; i < 4; ++i)
    t[ty + i * 8][tx] = s[(long)(r0 + ty + i * 8) * ss + c0 + tx];
  __syncthreads();
#pragma unroll
  for (int i = 0; i < 4; ++i)
    d[(long)(c0 + ty + i * 8) * ds + r0 + tx] = t[tx][ty + i * 8];
}

__global__ __launch_bounds__(256)
void convert_f32_to_bf16(const float* __restrict__ src, u16* __restrict__ dst, long n4) {
  long i = (long)blockIdx.x * 256 + threadIdx.x;
  if (i < n4) {
    float4 v = ((const float4*)src)[i];
    *(u16x4*)(dst + i * 4) = (u16x4){ f2bf(v.x), f2bf(v.y), f2bf(v.z), f2bf(v.w) };
  }
}

__global__ __launch_bounds__(256)
void cam_tanh_kernel(const float* __restrict__ ctx, const float* __restrict__ gate,
                     u16* __restrict__ out, int n) {
  int i = blockIdx.x * 256 + threadIdx.x;
  if (i < n) {
    int d = i & 127;
    out[i] = f2bf(tanhf(ctx[i] * gate[d]));
  }
}

__global__ __launch_bounds__(256)
void zero_f32(float* __restrict__ p, int n) {
  int i = blockIdx.x * 256 + threadIdx.x;
  if (i < n) p[i] = 0.f;
}

__global__ void calc_lw_kernel(const float* w0, const float* w1, float* lw) {
  *lw = 1.f / (1.f + __expf(-(w0[0] + 0.5f * w1[0])));
}

extern "C" void kernel_launch(void* const* d_in, const int* in_sizes, int n_in,
                              void* d_out, int out_size, void* d_ws, size_t ws_size,
                              hipStream_t stream) {
  const float* hs       = (const float*)d_in[0];
  const float* c_attn_w = (const float*)d_in[1];
  const float* c_attn_b = (const float*)d_in[2];
  const float* c_proj_w = (const float*)d_in[3];
  const float* c_proj_b = (const float*)d_in[4];
  const float* cam_gate = (const float*)d_in[5];
  const float* cam_w0   = (const float*)d_in[6];
  const float* cam_w1   = (const float*)d_in[7];
  float* out = (float*)d_out;

  char* w = (char*)d_ws;
  float* lw      = (float*)(w + 0);
  u16*   hs_b    = (u16*)(w + 256);                  // 16 MB (reused as baseA)
  u16*   waT_b   = (u16*)(w + 256 + 16777216UL);     // 24 MB
  u16*   wpT_b   = (u16*)(w + 256 + 41943040UL);     // 8 MB
  u16*   qkv_b   = (u16*)(w + 256 + 50331648UL);     // 48 MB
  u16*   vT_b    = (u16*)(w + 256 + 100663296UL);    // 16 MB
  float* scoresF = (float*)(w + 256 + 117440512UL);  // 32 MB (reused as ctxE bf16)
  float* camS    = (float*)(w + 256 + 150994944UL);  // 32 MB (reused as P bf16)
  float* ctxF    = (float*)(w + 256 + 184549376UL);  // 2 MB
  u16*   camT_b  = (u16*)(w + 256 + 186646528UL);    // 1 MB
  u16* baseA_b = hs_b;
  u16* P_b     = (u16*)camS;
  u16* ctxE_b  = (u16*)scoresF;

  dim3 b256(256);

  // allow 128 KiB dynamic LDS for the 256^2 kernel (host-side, capture-safe)
  {
    auto* kfn = gemm256<true, true>;
    hipFuncSetAttribute((const void*)kfn, hipFuncAttributeMaxDynamicSharedMemorySize, 131072);
  }

  calc_lw_kernel<<<dim3(1), dim3(1), 0, stream>>>(cam_w0, cam_w1, lw);
  convert_f32_to_bf16<<<dim3(8192), b256, 0, stream>>>(hs, hs_b, 2097152L);
  transpose_f32_to_bf16<<<dim3(192, 64), dim3(32, 8), 0, stream>>>(c_attn_w, waT_b, 2048, 6144);
  transpose_f32_to_bf16<<<dim3(64, 64), dim3(32, 8), 0, stream>>>(c_proj_w, wpT_b, 2048, 2048);

  // GEMM1: qkv (4096x6144 bf16) = hs @ W_attn + b  — 256^2 pipelined kernel
  gemm256<true, true><<<dim3(384, 1, 1), dim3(512), 131072, stream>>>(
      hs_b, 2048, 0L, waT_b, 2048, 0L, qkv_b, 6144, 0L,
      2048, 1.f, nullptr, c_attn_b, 24);

  // V^T per batch (2048x2048 each)
  transpose_bf16_batched<<<dim3(64, 64, 2), dim3(32, 8), 0, stream>>>(
      qkv_b + 4096, 6144, 2048L * 6144, vT_b, 2048, 2048L * 2048);

  // GEMM2: scores = Q @ K^T * SCALE (f32)
  gemm_bt<false, false, false><<<dim3(16, 16, 2), b256, 0, stream>>>(
      qkv_b, 6144, 2048L * 6144, qkv_b + 2048, 6144, 2048L * 6144,
      scoresF, 2048, 2048L * 2048, 2048, SCALE_QK, nullptr, nullptr);

  // GEMM3: camS = Q_cam @ K_cam^T * SCALE (K=128, f32)
  gemm_bt<false, false, false><<<dim3(16, 16, 2), b256, 0, stream>>>(
      qkv_b, 6144, 2048L * 6144, qkv_b + 2048, 6144, 2048L * 6144,
      camS, 2048, 2048L * 2048, 128, SCALE_QK, nullptr, nullptr);

  // base_A = softmax(camS) -> bf16
  softmax_rows2048<<<dim3(4096), b256, 0, stream>>>(camS, baseA_b);

  // GEMM4: cam_ctx (2048x128 f32 per batch) = base_A @ V_cam — split-K x8
  zero_f32<<<dim3(2048), b256, 0, stream>>>(ctxF, 524288);
  gemm_bt_splitk<<<dim3(1, 16, 16), b256, 0, stream>>>(
      baseA_b, 2048, 2048L * 2048, vT_b, 2048, 2048L * 2048,
      ctxF, 128, 2048L * 128, 256, 1.f);

  // camT = tanh(cam_ctx * gate) -> bf16
  cam_tanh_kernel<<<dim3(2048), b256, 0, stream>>>(ctxF, cam_gate, camT_b, 524288);

  // GEMM5: scores += camT @ K_cam^T * (SCALE * layer_weight)   (K=128, accumulate)
  gemm_bt<false, true, false><<<dim3(16, 16, 2), b256, 0, stream>>>(
      camT_b, 128, 2048L * 128, qkv_b + 2048, 6144, 2048L * 6144,
      scoresF, 2048, 2048L * 2048, 128, SCALE_QK, lw, nullptr);

  // P = softmax(scores) -> bf16
  softmax_rows2048<<<dim3(4096), b256, 0, stream>>>(scoresF, P_b);

  // GEMM6: context (bf16) = P @ V
  gemm_bt<true, false, false><<<dim3(16, 16, 2), b256, 0, stream>>>(
      P_b, 2048, 2048L * 2048, vT_b, 2048, 2048L * 2048,
      ctxE_b, 2048, 2048L * 2048, 2048, 1.f, nullptr, nullptr);

  // GEMM7: out (f32) = context @ W_proj + b
  gemm_bt<false, false, true><<<dim3(16, 32, 1), b256, 0, stream>>>(
      ctxE_b, 2048, 0L, wpT_b, 2048, 0L, out, 2048, 0L,
      2048, 1.f, nullptr, c_proj_b);
}

// Round 3
// 392.423 us; speedup vs baseline: 1.1056x; 1.0187x over previous
//
#include <hip/hip_runtime.h>
#include <hip/hip_bf16.h>

typedef unsigned short u16;
typedef __attribute__((ext_vector_type(8))) __bf16 bf16x8;
typedef __attribute__((ext_vector_type(4))) float f32x4;
typedef __attribute__((ext_vector_type(4))) unsigned short u16x4;

#define SCALE_QK 0.08838834764831845f

__device__ __forceinline__ u16 f2bf(float x) {
  union { float f; unsigned u; } v; v.f = x;
  unsigned r = v.u + 0x7fffu + ((v.u >> 16) & 1u);
  return (u16)(r >> 16);
}

__device__ __forceinline__ void gload_lds16(const u16* g, u16* l) {
  __builtin_amdgcn_global_load_lds(
      (const __attribute__((address_space(1))) unsigned*)g,
      (__attribute__((address_space(3))) unsigned*)l, 16, 0, 0);
}

#define CFENCE() asm volatile("" ::: "memory")

// ===========================================================================
// 256x256 tile, BK=64, 2-deep LDS double-buffer, 4 phases per K-tile.
// Stage units sliced by K-half: u0=A_kk0, u2=B_kk0, u1=A_kk1, u3=B_kk1
// (issue order u0,u2,u1,u3). Phase p reads only units staged 4 phases ago:
//   phi0 needs u0,u2 -> vmcnt(4); phi2 needs u1,u3 -> vmcnt(4). Never 0 in
// steady state (T4). 16 MFMA per phase wrapped in setprio (T5).
// LDS per buffer (u16 elems): A_kk0[256][32] @0, A_kk1 @8192, B_kk0 @16384,
// B_kk1 @24576. Swizzle (T2): elem slot g -> g ^ ((row>>1)&3) (16B units),
// applied on global source (staging) and ds_read address; dest stays linear
// (rule #21). 8 waves = 2M x 4N, wave tile 128x64, acc[8][4].
// Optional second K-segment (TWO_SEG) accumulates into the same acc.
// ===========================================================================
template<bool OUT_BF16, bool HAS_BIAS, bool TWO_SEG>
__global__ __launch_bounds__(512, 2)
void gemm256_8ph(const u16* __restrict__ A1, int lda1, long sA1,
                 const u16* __restrict__ B1, int ldb1, long sB1, int K1,
                 const u16* __restrict__ A2, int lda2, long sA2,
                 const u16* __restrict__ B2, int ldb2, long sB2, int K2,
                 void* __restrict__ Cv, int ldc, long sC,
                 float scale, const float* __restrict__ bias, int nbx)
{
  extern __shared__ u16 lds[];
  const int bz = blockIdx.z;

  // bijective XCD swizzle (m204)
  const int nwg = gridDim.x;
  const int orig = blockIdx.x;
  const int q8 = nwg >> 3, r8 = nwg & 7;
  const int xcd = orig & 7, lp = orig >> 3;
  const int wg = (xcd < r8 ? xcd * (q8 + 1) : r8 * (q8 + 1) + (xcd - r8) * q8) + lp;
  const int bx = wg % nbx, by = wg / nbx;
  const long m0 = (long)by * 256, n0 = (long)bx * 256;

  const int tid = threadIdx.x;
  const int wid = tid >> 6, lane = tid & 63;
  const int wm = wid >> 2, wn = wid & 3;     // wave tile: rows wm*128, cols wn*64
  const int rl = lane & 15, g = lane >> 4;
  const int swk = ((g ^ ((rl >> 1) & 3)) << 3);   // swizzled 8-elem slot

  int aoff[8], boff[4];
#pragma unroll
  for (int i = 0; i < 8; ++i)
    aoff[i] = (wm * 128 + i * 16 + rl) * 32 + swk;
#pragma unroll
  for (int j = 0; j < 4; ++j)
    boff[j] = 16384 + (wn * 64 + j * 16 + rl) * 32 + swk;

  // staging geometry: thread covers row Rl (and Rl+128), 8 elems at swizzled col
  const int Rl = tid >> 2;
  const int scol = (((tid & 3) ^ ((tid >> 3) & 3)) << 3);
  const int sdst = wid * 512;   // wave-uniform LDS element offset

  f32x4 acc[8][4];
#pragma unroll
  for (int i = 0; i < 8; ++i)
#pragma unroll
    for (int j = 0; j < 4; ++j) acc[i][j] = (f32x4){0.f, 0.f, 0.f, 0.f};

#define STAGE_A(KK, KB, BQ)                                                  \
  gload_lds16(rA0 + (KB) + (KK) * 32, (BQ) + (KK) * 8192 + sdst);            \
  gload_lds16(rA1 + (KB) + (KK) * 32, (BQ) + (KK) * 8192 + 4096 + sdst);
#define STAGE_B(KK, KB, BQ)                                                  \
  gload_lds16(rB0 + (KB) + (KK) * 32, (BQ) + 16384 + (KK) * 8192 + sdst);    \
  gload_lds16(rB1 + (KB) + (KK) * 32, (BQ) + 16384 + (KK) * 8192 + 4096 + sdst);
#define PHASE_MFMA(IH)                                                       \
  __builtin_amdgcn_s_setprio(1);                                             \
  _Pragma("unroll")                                                          \
  for (int i = 0; i < 4; ++i)                                                \
    _Pragma("unroll")                                                        \
    for (int j = 0; j < 4; ++j)                                              \
      acc[(IH) * 4 + i][j] = __builtin_amdgcn_mfma_f32_16x16x32_bf16(        \
          av[i], bv[j], acc[(IH) * 4 + i][j], 0, 0, 0);                      \
  __builtin_amdgcn_s_setprio(0);

  const int NSEG = TWO_SEG ? 2 : 1;
#pragma unroll 1
  for (int seg = 0; seg < NSEG; ++seg) {
    const u16* Ap = (seg == 0) ? (A1 + (long)bz * sA1) : (A2 + (long)bz * sA2);
    const u16* Bp = (seg == 0) ? (B1 + (long)bz * sB1) : (B2 + (long)bz * sB2);
    const int lda = (seg == 0) ? lda1 : lda2;
    const int ldb = (seg == 0) ? ldb1 : ldb2;
    const int K   = (seg == 0) ? K1 : K2;
    const int NT  = K >> 6;

    const u16* rA0 = Ap + (m0 + Rl) * (long)lda + scol;
    const u16* rA1 = Ap + (m0 + Rl + 128) * (long)lda + scol;
    const u16* rB0 = Bp + (n0 + Rl) * (long)ldb + scol;
    const u16* rB1 = Bp + (n0 + Rl + 128) * (long)ldb + scol;

    // prologue: stage tile 0 (units u0,u2,u1,u3) into buf0
    __builtin_amdgcn_s_barrier();
    CFENCE();
    STAGE_A(0, 0, lds);
    STAGE_B(0, 0, lds);
    STAGE_A(1, 0, lds);
    STAGE_B(1, 0, lds);
    CFENCE();

#pragma unroll 1
    for (int t = 0; t < NT; ++t) {
      const u16* bp = lds + (t & 1) * 32768;
      u16* bq = lds + ((t + 1) & 1) * 32768;
      const bool hn = (t + 1) < NT;
      const int kn = (t + 1) << 6;

      bf16x8 av[4], bv[4];

      // ---- phi0: needs u0(t), u2(t)
      asm volatile("s_waitcnt vmcnt(4)" ::: "memory");
      __builtin_amdgcn_s_barrier();
      CFENCE();
      if (hn) { STAGE_A(0, kn, bq); }
#pragma unroll
      for (int i = 0; i < 4; ++i) av[i] = *(const bf16x8*)(bp + aoff[i]);
#pragma unroll
      for (int j = 0; j < 4; ++j) bv[j] = *(const bf16x8*)(bp + boff[j]);
      PHASE_MFMA(0)
      CFENCE();

      // ---- phi1
      if (hn) { STAGE_B(0, kn, bq); }
#pragma unroll
      for (int i = 0; i < 4; ++i) av[i] = *(const bf16x8*)(bp + aoff[4 + i]);
      PHASE_MFMA(1)
      CFENCE();

      // ---- phi2: needs u1(t), u3(t)
      if (hn) { asm volatile("s_waitcnt vmcnt(4)" ::: "memory"); }
      else    { asm volatile("s_waitcnt vmcnt(0)" ::: "memory"); }
      __builtin_amdgcn_s_barrier();
      CFENCE();
      if (hn) { STAGE_A(1, kn, bq); }
#pragma unroll
      for (int i = 0; i < 4; ++i) av[i] = *(const bf16x8*)(bp + 8192 + aoff[i]);
#pragma unroll
      for (int j = 0; j < 4; ++j) bv[j] = *(const bf16x8*)(bp + 8192 + boff[j]);
      PHASE_MFMA(0)
      CFENCE();

      // ---- phi3
      if (hn) { STAGE_B(1, kn, bq); }
#pragma unroll
      for (int i = 0; i < 4; ++i) av[i] = *(const bf16x8*)(bp + 8192 + aoff[4 + i]);
      PHASE_MFMA(1)
      CFENCE();
    }
  }
#undef STAGE_A
#undef STAGE_B
#undef PHASE_MFMA

  const int r0 = (lane >> 4) << 2;
  const int cL = lane & 15;
#pragma unroll
  for (int i = 0; i < 8; ++i) {
#pragma unroll
    for (int j = 0; j < 4; ++j) {
      const long row = m0 + wm * 128 + i * 16 + r0;
      const long col = n0 + wn * 64 + j * 16 + cL;
      float bvs = 0.f;
      if (HAS_BIAS) bvs = bias[col];
      if (OUT_BF16) {
        u16* Cp = (u16*)Cv + (long)bz * sC;
#pragma unroll
        for (int r = 0; r < 4; ++r)
          Cp[(row + r) * ldc + col] = f2bf(acc[i][j][r] * scale + bvs);
      } else {
        float* Cp = (float*)Cv + (long)bz * sC;
#pragma unroll
        for (int r = 0; r < 4; ++r)
          Cp[(row + r) * ldc + col] = acc[i][j][r] * scale + bvs;
      }
    }
  }
}

// ---------------------------------------------------------------------------
// Legacy 128x128 kernel for GEMM3 (K=128).
// ---------------------------------------------------------------------------
template<bool OUT_BF16, bool HAS_BIAS>
__global__ __launch_bounds__(256)
void gemm_bt(const u16* __restrict__ A, int lda, long sA,
             const u16* __restrict__ B, int ldb, long sB,
             void* __restrict__ Cv, int ldc, long sC,
             int K, float scale, const float* __restrict__ bias)
{
  __shared__ u16 As[128 * 64];
  __shared__ u16 Bs[128 * 64];
  const int bz   = blockIdx.z;
  const u16* Ap  = A + (long)bz * sA;
  const u16* Bp  = B + (long)bz * sB;
  const int tid  = threadIdx.x;
  const int wid  = tid >> 6;
  const int lane = tid & 63;
  const long m0  = (long)blockIdx.y * 128;
  const long n0  = (long)blockIdx.x * 128;
  const int lrow = lane >> 3;
  const int lk   = (lane & 7) << 3;
  const int wr   = wid >> 1, wc = wid & 1;

  f32x4 acc[4][4];
#pragma unroll
  for (int i = 0; i < 4; ++i)
#pragma unroll
    for (int j = 0; j < 4; ++j) acc[i][j] = (f32x4){0.f, 0.f, 0.f, 0.f};

  for (int k0 = 0; k0 < K; k0 += 64) {
#pragma unroll
    for (int c4 = 0; c4 < 4; ++c4) {
      const int chunk = (wid << 2) + c4;
      gload_lds16(Ap + (m0 + (chunk << 3) + lrow) * lda + k0 + lk, &As[chunk << 9]);
      gload_lds16(Bp + (n0 + (chunk << 3) + lrow) * ldb + k0 + lk, &Bs[chunk << 9]);
    }
    __syncthreads();
#pragma unroll
    for (int kk = 0; kk < 2; ++kk) {
      bf16x8 af[4], bfr[4];
      const int kof   = (kk << 5) + ((lane >> 4) << 3);
      const int rbase = lane & 15;
#pragma unroll
      for (int i = 0; i < 4; ++i)
        af[i] = *(const bf16x8*)&As[(((wr << 6) + (i << 4) + rbase) << 6) + kof];
#pragma unroll
      for (int j = 0; j < 4; ++j)
        bfr[j] = *(const bf16x8*)&Bs[(((wc << 6) + (j << 4) + rbase) << 6) + kof];
#pragma unroll
      for (int i = 0; i < 4; ++i)
#pragma unroll
        for (int j = 0; j < 4; ++j)
          acc[i][j] = __builtin_amdgcn_mfma_f32_16x16x32_bf16(af[i], bfr[j], acc[i][j], 0, 0, 0);
    }
    __syncthreads();
  }

  const int r0 = (lane >> 4) << 2;
  const int cL = lane & 15;
#pragma unroll
  for (int i = 0; i < 4; ++i) {
#pragma unroll
    for (int j = 0; j < 4; ++j) {
      const long row = m0 + (wr << 6) + (i << 4) + r0;
      const long col = n0 + (wc << 6) + (j << 4) + cL;
      float bv = 0.f;
      if (HAS_BIAS) bv = bias[col];
      if (OUT_BF16) {
        u16* Cp = (u16*)Cv + (long)bz * sC;
#pragma unroll
        for (int r = 0; r < 4; ++r)
          Cp[(row + r) * ldc + col] = f2bf(acc[i][j][r] * scale + bv);
      } else {
        float* Cp = (float*)Cv + (long)bz * sC;
#pragma unroll
        for (int r = 0; r < 4; ++r)
          Cp[(row + r) * ldc + col] = acc[i][j][r] * scale + bv;
      }
    }
  }
}

// Split-K (x8) variant for skinny GEMM4: atomicAdd f32 epilogue.
__global__ __launch_bounds__(256)
void gemm_bt_splitk(const u16* __restrict__ A, int lda, long sA,
                    const u16* __restrict__ B, int ldb, long sB,
                    float* __restrict__ C, int ldc, long sC,
                    int Kslice, float scale)
{
  __shared__ u16 As[128 * 64];
  __shared__ u16 Bs[128 * 64];
  const int ks = blockIdx.z & 7;
  const int bz = blockIdx.z >> 3;
  const u16* Ap  = A + (long)bz * sA + ks * Kslice;
  const u16* Bp  = B + (long)bz * sB + ks * Kslice;
  const int tid  = threadIdx.x;
  const int wid  = tid >> 6;
  const int lane = tid & 63;
  const long m0  = (long)blockIdx.y * 128;
  const long n0  = (long)blockIdx.x * 128;
  const int lrow = lane >> 3;
  const int lk   = (lane & 7) << 3;
  const int wr   = wid >> 1, wc = wid & 1;

  f32x4 acc[4][4];
#pragma unroll
  for (int i = 0; i < 4; ++i)
#pragma unroll
    for (int j = 0; j < 4; ++j) acc[i][j] = (f32x4){0.f, 0.f, 0.f, 0.f};

  for (int k0 = 0; k0 < Kslice; k0 += 64) {
#pragma unroll
    for (int c4 = 0; c4 < 4; ++c4) {
      const int chunk = (wid << 2) + c4;
      gload_lds16(Ap + (m0 + (chunk << 3) + lrow) * lda + k0 + lk, &As[chunk << 9]);
      gload_lds16(Bp + (n0 + (chunk << 3) + lrow) * ldb + k0 + lk, &Bs[chunk << 9]);
    }
    __syncthreads();
#pragma unroll
    for (int kk = 0; kk < 2; ++kk) {
      bf16x8 af[4], bfr[4];
      const int kof   = (kk << 5) + ((lane >> 4) << 3);
      const int rbase = lane & 15;
#pragma unroll
      for (int i = 0; i < 4; ++i)
        af[i] = *(const bf16x8*)&As[(((wr << 6) + (i << 4) + rbase) << 6) + kof];
#pragma unroll
      for (int j = 0; j < 4; ++j)
        bfr[j] = *(const bf16x8*)&Bs[(((wc << 6) + (j << 4) + rbase) << 6) + kof];
#pragma unroll
      for (int i = 0; i < 4; ++i)
#pragma unroll
        for (int j = 0; j < 4; ++j)
          acc[i][j] = __builtin_amdgcn_mfma_f32_16x16x32_bf16(af[i], bfr[j], acc[i][j], 0, 0, 0);
    }
    __syncthreads();
  }

  const int r0 = (lane >> 4) << 2;
  const int cL = lane & 15;
  float* Cp = C + (long)bz * sC;
#pragma unroll
  for (int i = 0; i < 4; ++i) {
#pragma unroll
    for (int j = 0; j < 4; ++j) {
      const long row = m0 + (wr << 6) + (i << 4) + r0;
      const long col = n0 + (wc << 6) + (j << 4) + cL;
#pragma unroll
      for (int r = 0; r < 4; ++r)
        atomicAdd(&Cp[(row + r) * ldc + col], acc[i][j][r] * scale);
    }
  }
}

// Row softmax over 2048 f32 -> bf16. One block (256 thr) per row.
__global__ __launch_bounds__(256)
void softmax_rows2048(const float* __restrict__ src, u16* __restrict__ dst) {
  const long row = blockIdx.x;
  const float4* s = (const float4*)(src + row * 2048);
  const int tid = threadIdx.x;
  float4 a = s[tid * 2], b = s[tid * 2 + 1];
  float m = fmaxf(fmaxf(fmaxf(a.x, a.y), fmaxf(a.z, a.w)),
                  fmaxf(fmaxf(b.x, b.y), fmaxf(b.z, b.w)));
#pragma unroll
  for (int o = 32; o > 0; o >>= 1) m = fmaxf(m, __shfl_xor(m, o));
  __shared__ float redm[4];
  __shared__ float reds[4];
  if ((tid & 63) == 0) redm[tid >> 6] = m;
  __syncthreads();
  m = fmaxf(fmaxf(redm[0], redm[1]), fmaxf(redm[2], redm[3]));
  float e[8];
  e[0] = __expf(a.x - m); e[1] = __expf(a.y - m); e[2] = __expf(a.z - m); e[3] = __expf(a.w - m);
  e[4] = __expf(b.x - m); e[5] = __expf(b.y - m); e[6] = __expf(b.z - m); e[7] = __expf(b.w - m);
  float sum = e[0] + e[1] + e[2] + e[3] + e[4] + e[5] + e[6] + e[7];
#pragma unroll
  for (int o = 32; o > 0; o >>= 1) sum += __shfl_xor(sum, o);
  if ((tid & 63) == 0) reds[tid >> 6] = sum;
  __syncthreads();
  sum = reds[0] + reds[1] + reds[2] + reds[3];
  const float inv = 1.f / sum;
  u16x4 o1 = { f2bf(e[0] * inv), f2bf(e[1] * inv), f2bf(e[2] * inv), f2bf(e[3] * inv) };
  u16x4 o2 = { f2bf(e[4] * inv), f2bf(e[5] * inv), f2bf(e[6] * inv), f2bf(e[7] * inv) };
  u16x4* d = (u16x4*)(dst + row * 2048);
  d[tid * 2]     = o1;
  d[tid * 2 + 1] = o2;
}

__global__ void transpose_f32_to_bf16(const float* __restrict__ src, u16* __restrict__ dst,
                                      int R, int C) {
  __shared__ float t[32][33];
  const int c0 = blockIdx.x * 32, r0 = blockIdx.y * 32;
  const int tx = threadIdx.x, ty = threadIdx.y;
#pragma unroll
  for (int i = 0; i < 4; ++i)
    t[ty + i * 8][tx] = src[(long)(r0 + ty + i * 8) * C + c0 + tx];
  __syncthreads();
#pragma unroll
  for (int i = 0; i < 4; ++i)
    dst[(long)(c0 + ty + i * 8) * R + r0 + tx] = f2bf(t[tx][ty + i * 8]);
}

__global__ void transpose_bf16_batched(const u16* __restrict__ src, int ss, long sbat,
                                       u16* __restrict__ dst, int ds, long dbat) {
  __shared__ u16 t[32][33];
  const u16* s = src + (long)blockIdx.z * sbat;
  u16* d = dst + (long)blockIdx.z * dbat;
  const int c0 = blockIdx.x * 32, r0 = blockIdx.y * 32;
  const int tx = threadIdx.x, ty = threadIdx.y;
#pragma unroll
  for (int i = 0; i < 4; ++i)
    t[ty + i * 8][tx] = s[(long)(r0 + ty + i * 8) * ss + c0 + tx];
  __syncthreads();
#pragma unroll
  for (int i = 0; i < 4; ++i)
    d[(long)(c0 + ty + i * 8) * ds + r0 + tx] = t[tx][ty + i * 8];
}

__global__ __launch_bounds__(256)
void convert_f32_to_bf16(const float* __restrict__ src, u16* __restrict__ dst, long n4) {
  long i = (long)blockIdx.x * 256 + threadIdx.x;
  if (i < n4) {
    float4 v = ((const float4*)src)[i];
    *(u16x4*)(dst + i * 4) = (u16x4){ f2bf(v.x), f2bf(v.y), f2bf(v.z), f2bf(v.w) };
  }
}

// camT = tanh(ctx * gate) * lw  (lw folded here so GEMM2' uses plain SCALE)
__global__ __launch_bounds__(256)
void cam_tanh_kernel(const float* __restrict__ ctx, const float* __restrict__ gate,
                     const float* __restrict__ lw, u16* __restrict__ out, int n) {
  int i = blockIdx.x * 256 + threadIdx.x;
  if (i < n) {
    int d = i & 127;
    out[i] = f2bf(tanhf(ctx[i] * gate[d]) * lw[0]);
  }
}

__global__ __launch_bounds__(256)
void zero_f32(float* __restrict__ p, int n) {
  int i = blockIdx.x * 256 + threadIdx.x;
  if (i < n) p[i] = 0.f;
}

__global__ void calc_lw_kernel(const float* w0, const float* w1, float* lw) {
  *lw = 1.f / (1.f + __expf(-(w0[0] + 0.5f * w1[0])));
}

extern "C" void kernel_launch(void* const* d_in, const int* in_sizes, int n_in,
                              void* d_out, int out_size, void* d_ws, size_t ws_size,
                              hipStream_t stream) {
  const float* hs       = (const float*)d_in[0];
  const float* c_attn_w = (const float*)d_in[1];
  const float* c_attn_b = (const float*)d_in[2];
  const float* c_proj_w = (const float*)d_in[3];
  const float* c_proj_b = (const float*)d_in[4];
  const float* cam_gate = (const float*)d_in[5];
  const float* cam_w0   = (const float*)d_in[6];
  const float* cam_w1   = (const float*)d_in[7];
  float* out = (float*)d_out;

  char* w = (char*)d_ws;
  float* lw      = (float*)(w + 0);
  u16*   hs_b    = (u16*)(w + 256);                  // 16 MB (reused as baseA)
  u16*   waT_b   = (u16*)(w + 256 + 16777216UL);     // 24 MB
  u16*   wpT_b   = (u16*)(w + 256 + 41943040UL);     // 8 MB
  u16*   qkv_b   = (u16*)(w + 256 + 50331648UL);     // 48 MB
  u16*   vT_b    = (u16*)(w + 256 + 100663296UL);    // 16 MB
  float* scoresF = (float*)(w + 256 + 117440512UL);  // 32 MB (reused as ctxE bf16)
  float* camS    = (float*)(w + 256 + 150994944UL);  // 32 MB (reused as P bf16)
  float* ctxF    = (float*)(w + 256 + 184549376UL);  // 2 MB
  u16*   camT_b  = (u16*)(w + 256 + 186646528UL);    // 1 MB
  u16* baseA_b = hs_b;
  u16* P_b     = (u16*)camS;
  u16* ctxE_b  = (u16*)scoresF;

  dim3 b256(256);

  // allow 128 KiB dynamic LDS for each gemm256_8ph instantiation
  hipFuncSetAttribute((const void*)gemm256_8ph<true,  true,  false>,
                      hipFuncAttributeMaxDynamicSharedMemorySize, 131072);
  hipFuncSetAttribute((const void*)gemm256_8ph<false, false, true>,
                      hipFuncAttributeMaxDynamicSharedMemorySize, 131072);
  hipFuncSetAttribute((const void*)gemm256_8ph<true,  false, false>,
                      hipFuncAttributeMaxDynamicSharedMemorySize, 131072);
  hipFuncSetAttribute((const void*)gemm256_8ph<false, true,  false>,
                      hipFuncAttributeMaxDynamicSharedMemorySize, 131072);

  calc_lw_kernel<<<dim3(1), dim3(1), 0, stream>>>(cam_w0, cam_w1, lw);
  convert_f32_to_bf16<<<dim3(8192), b256, 0, stream>>>(hs, hs_b, 2097152L);
  transpose_f32_to_bf16<<<dim3(192, 64), dim3(32, 8), 0, stream>>>(c_attn_w, waT_b, 2048, 6144);
  transpose_f32_to_bf16<<<dim3(64, 64), dim3(32, 8), 0, stream>>>(c_proj_w, wpT_b, 2048, 2048);

  // GEMM1: qkv (4096x6144 bf16) = hs @ W_attn + b
  gemm256_8ph<true, true, false><<<dim3(384, 1, 1), dim3(512), 131072, stream>>>(
      hs_b, 2048, 0L, waT_b, 2048, 0L, 2048,
      nullptr, 0, 0L, nullptr, 0, 0L, 0,
      qkv_b, 6144, 0L, 1.f, c_attn_b, 24);

  // V^T per batch (2048x2048 each)
  transpose_bf16_batched<<<dim3(64, 64, 2), dim3(32, 8), 0, stream>>>(
      qkv_b + 4096, 6144, 2048L * 6144, vT_b, 2048, 2048L * 2048);

  // GEMM3: camS = Q_cam @ K_cam^T * SCALE (K=128, f32)
  gemm_bt<false, false><<<dim3(16, 16, 2), b256, 0, stream>>>(
      qkv_b, 6144, 2048L * 6144, qkv_b + 2048, 6144, 2048L * 6144,
      camS, 2048, 2048L * 2048, 128, SCALE_QK, nullptr);

  // base_A = softmax(camS) -> bf16
  softmax_rows2048<<<dim3(4096), b256, 0, stream>>>(camS, baseA_b);

  // GEMM4: cam_ctx (2048x128 f32 per batch) = base_A @ V_cam — split-K x8
  zero_f32<<<dim3(2048), b256, 0, stream>>>(ctxF, 524288);
  gemm_bt_splitk<<<dim3(1, 16, 16), b256, 0, stream>>>(
      baseA_b, 2048, 2048L * 2048, vT_b, 2048, 2048L * 2048,
      ctxF, 128, 2048L * 128, 256, 1.f);

  // camT = tanh(cam_ctx * gate) * lw -> bf16
  cam_tanh_kernel<<<dim3(2048), b256, 0, stream>>>(ctxF, cam_gate, lw, camT_b, 524288);

  // GEMM2' (fused GEMM5): scores = SCALE*( Q@K^T + camT@K_cam^T ), f32
  gemm256_8ph<false, false, true><<<dim3(64, 1, 2), dim3(512), 131072, stream>>>(
      qkv_b, 6144, 2048L * 6144, qkv_b + 2048, 6144, 2048L * 6144, 2048,
      camT_b, 128, 2048L * 128, qkv_b + 2048, 6144, 2048L * 6144, 128,
      scoresF, 2048, 2048L * 2048, SCALE_QK, nullptr, 8);

  // P = softmax(scores) -> bf16
  softmax_rows2048<<<dim3(4096), b256, 0, stream>>>(scoresF, P_b);

  // GEMM6: context (bf16) = P @ V
  gemm256_8ph<true, false, false><<<dim3(64, 1, 2), dim3(512), 131072, stream>>>(
      P_b, 2048, 2048L * 2048, vT_b, 2048, 2048L * 2048, 2048,
      nullptr, 0, 0L, nullptr, 0, 0L, 0,
      ctxE_b, 2048, 2048L * 2048, 1.f, nullptr, 8);

  // GEMM7: out (f32) = context @ W_proj + b  (batches stacked: M=4096)
  gemm256_8ph<false, true, false><<<dim3(128, 1, 1), dim3(512), 131072, stream>>>(
      ctxE_b, 2048, 0L, wpT_b, 2048, 0L, 2048,
      nullptr, 0, 0L, nullptr, 0, 0L, 0,
      out, 2048, 0L, 1.f, c_proj_b, 8);
}

// Round 4
// 349.955 us; speedup vs baseline: 1.2398x; 1.1214x over previous
//
#include <hip/hip_runtime.h>
#include <hip/hip_bf16.h>

typedef unsigned short u16;
typedef __attribute__((ext_vector_type(8))) __bf16 bf16x8;
typedef __attribute__((ext_vector_type(4))) float f32x4;
typedef __attribute__((ext_vector_type(4))) unsigned short u16x4;

#define SCALE_QK 0.08838834764831845f

__device__ __forceinline__ u16 f2bf(float x) {
  union { float f; unsigned u; } v; v.f = x;
  unsigned r = v.u + 0x7fffu + ((v.u >> 16) & 1u);
  return (u16)(r >> 16);
}

__device__ __forceinline__ void gload_lds16(const u16* g, u16* l) {
  __builtin_amdgcn_global_load_lds(
      (const __attribute__((address_space(1))) unsigned*)g,
      (__attribute__((address_space(3))) unsigned*)l, 16, 0, 0);
}

#define CFENCE() asm volatile("" ::: "memory")
#define WAITV(N) asm volatile("s_waitcnt vmcnt(" #N ")" ::: "memory")

// Phase tail: barrier -> lgkm(0) -> sched_barrier -> prio1 MFMA cluster prio0 -> barrier
#define MM_PROLOG()                                                      \
  CFENCE(); __builtin_amdgcn_s_barrier();                                \
  asm volatile("s_waitcnt lgkmcnt(0)" ::: "memory");                     \
  __builtin_amdgcn_sched_barrier(0);                                     \
  __builtin_amdgcn_s_setprio(1);
#define MM_EPILOG()                                                      \
  __builtin_amdgcn_s_setprio(0);                                         \
  CFENCE(); __builtin_amdgcn_s_barrier(); CFENCE();

// ===========================================================================
// g256: 256x256 tile, BK=64, kk-half LDS slots (4-slot rotation per matrix),
// 4 phases/K-tile, unit staging (1 x 16KB half per phase, 6-unit lead),
// steady vmcnt(8) at p1/p3 only. 8 waves 2Mx4N. LDS 128 KiB.
// A slot h&3: [256][32] elems @ slot*8192 ; B region at elem 32768, same.
// Swizzle: 8-elem group g' = g ^ ((row>>1)&3); applied on global source and
// ds_read address; global_load_lds dest stays linear (rule #21).
// ===========================================================================
template<bool OUT_BF16, bool HAS_BIAS>
__global__ __launch_bounds__(512, 2)
void g256(const u16* __restrict__ A, int lda, long sA,
          const u16* __restrict__ B, int ldb, long sB,
          void* __restrict__ Cv, int ldc, long sC,
          int K, float scale, const float* __restrict__ bias, int nbx)
{
  extern __shared__ u16 lds[];
  const int bz = blockIdx.z;
  const int nwg = gridDim.x, orig = blockIdx.x;
  const int q8 = nwg >> 3, r8 = nwg & 7;
  const int xcd = orig & 7, lp = orig >> 3;
  const int wg = (xcd < r8 ? xcd * (q8 + 1) : r8 * (q8 + 1) + (xcd - r8) * q8) + lp;
  const int bx = wg % nbx, by = wg / nbx;
  const long m0 = (long)by * 256, n0 = (long)bx * 256;

  const int tid = threadIdx.x, wid = tid >> 6, lane = tid & 63;
  const int wm = wid >> 2, wn = wid & 3;
  const int rl = lane & 15, g = lane >> 4;
  const int sw = ((g ^ ((rl >> 1) & 3)) << 3);

  int aoff[8], boff[4];
#pragma unroll
  for (int i = 0; i < 8; ++i) aoff[i] = (wm * 128 + i * 16 + rl) * 32 + sw;
#pragma unroll
  for (int j = 0; j < 4; ++j) boff[j] = (wn * 64 + j * 16 + rl) * 32 + sw;

  const u16* Ab = A + (long)bz * sA + m0 * lda;
  const u16* Bb = B + (long)bz * sB + n0 * ldb;
  const int srow = tid >> 2;
  const int scolX = (((tid & 3) ^ ((srow >> 1) & 3)) << 3);

#define ST_A(H_) {                                                       \
    const u16* s_ = Ab + (long)srow * lda + (H_) * 32 + scolX;           \
    u16* d_ = lds + (((H_) & 3) * 8192) + tid * 8;                       \
    gload_lds16(s_, d_); gload_lds16(s_ + (long)128 * lda, d_ + 4096); }
#define ST_B(H_) {                                                       \
    const u16* s_ = Bb + (long)srow * ldb + (H_) * 32 + scolX;           \
    u16* d_ = lds + 32768 + (((H_) & 3) * 8192) + tid * 8;               \
    gload_lds16(s_, d_); gload_lds16(s_ + (long)128 * ldb, d_ + 4096); }
#define RDA(H_, IH) { const u16* aS_ = lds + ((H_) & 3) * 8192;          \
    _Pragma("unroll") for (int i = 0; i < 4; ++i)                        \
      av[i] = *(const bf16x8*)(aS_ + aoff[(IH) * 4 + i]); }
#define RDB(H_) { const u16* bS_ = lds + 32768 + ((H_) & 3) * 8192;      \
    _Pragma("unroll") for (int j = 0; j < 4; ++j)                        \
      bv[j] = *(const bf16x8*)(bS_ + boff[j]); }
#define MFMA16(IH)                                                       \
  MM_PROLOG();                                                           \
  _Pragma("unroll") for (int i = 0; i < 4; ++i)                          \
    _Pragma("unroll") for (int j = 0; j < 4; ++j)                        \
      acc[(IH) * 4 + i][j] = __builtin_amdgcn_mfma_f32_16x16x32_bf16(    \
          av[i], bv[j], acc[(IH) * 4 + i][j], 0, 0, 0);                  \
  MM_EPILOG();

  f32x4 acc[8][4];
#pragma unroll
  for (int i = 0; i < 8; ++i)
#pragma unroll
    for (int j = 0; j < 4; ++j) acc[i][j] = (f32x4){0.f, 0.f, 0.f, 0.f};

  const int NT = K >> 6;   // requires NT >= 2

  // prologue: units 0..5 = halves 0,1,2 of A and B
  ST_A(0); ST_B(0); ST_A(1); ST_B(1); ST_A(2); ST_B(2);
  WAITV(8);
  CFENCE(); __builtin_amdgcn_s_barrier(); CFENCE();

#pragma unroll 1
  for (int t = 0; t < NT - 2; ++t) {
    const int h0 = 2 * t, h1 = 2 * t + 1;
    bf16x8 av[4], bv[4];
    // p0
    RDA(h0, 0); RDB(h0); ST_A(h1 + 2); MFMA16(0);
    // p1
    RDA(h0, 1); ST_B(h1 + 2); WAITV(8); MFMA16(1);
    // p2
    RDA(h1, 0); RDB(h1); ST_A(h1 + 3); MFMA16(0);
    // p3
    RDA(h1, 1); ST_B(h1 + 3); WAITV(8); MFMA16(1);
  }
  { // tile NT-2: stage last halves at p0/p1 only
    const int h0 = 2 * NT - 4, h1 = 2 * NT - 3;
    bf16x8 av[4], bv[4];
    RDA(h0, 0); RDB(h0); ST_A(2 * NT - 1); MFMA16(0);
    RDA(h0, 1); ST_B(2 * NT - 1); WAITV(8); MFMA16(1);
    RDA(h1, 0); RDB(h1); MFMA16(0);
    RDA(h1, 1); WAITV(4); MFMA16(1);
  }
  { // tile NT-1: drain
    const int h0 = 2 * NT - 2, h1 = 2 * NT - 1;
    bf16x8 av[4], bv[4];
    RDA(h0, 0); RDB(h0); MFMA16(0);
    RDA(h0, 1); WAITV(0); MFMA16(1);
    RDA(h1, 0); RDB(h1); MFMA16(0);
    RDA(h1, 1); MFMA16(1);
  }
#undef ST_A
#undef ST_B
#undef RDA
#undef RDB
#undef MFMA16

  const int r0 = (lane >> 4) << 2;
  const int cL = lane & 15;
#pragma unroll
  for (int i = 0; i < 8; ++i) {
#pragma unroll
    for (int j = 0; j < 4; ++j) {
      const long row = m0 + wm * 128 + i * 16 + r0;
      const long col = n0 + wn * 64 + j * 16 + cL;
      float bvs = 0.f;
      if (HAS_BIAS) bvs = bias[col];
      if (OUT_BF16) {
        u16* Cp = (u16*)Cv + (long)bz * sC;
#pragma unroll
        for (int r = 0; r < 4; ++r)
          Cp[(row + r) * ldc + col] = f2bf(acc[i][j][r] * scale + bvs);
      } else {
        float* Cp = (float*)Cv + (long)bz * sC;
#pragma unroll
        for (int r = 0; r < 4; ++r)
          Cp[(row + r) * ldc + col] = acc[i][j][r] * scale + bvs;
      }
    }
  }
}

// ===========================================================================
// g128: 256x128 tile, BK=64, kk-half slots, ONE phase per kk-half
// (16 MFMA), 3 loads/half staged with 3-half lead -> steady vmcnt(6).
// 8 waves 4Mx2N, wave tile 64x64. LDS 96 KiB. Optional 2nd K-segment.
// ===========================================================================
template<bool OUT_BF16, bool HAS_BIAS, bool TWO_SEG>
__global__ __launch_bounds__(512, 2)
void g128(const u16* __restrict__ A1, int lda1, long sA1,
          const u16* __restrict__ B1, int ldb1, long sB1, int K1,
          const u16* __restrict__ A2, int lda2, long sA2,
          const u16* __restrict__ B2, int ldb2, long sB2, int K2,
          void* __restrict__ Cv, int ldc, long sC,
          float scale, const float* __restrict__ bias, int nbx)
{
  extern __shared__ u16 lds[];
  const int bz = blockIdx.z;
  const int nwg = gridDim.x, orig = blockIdx.x;
  const int q8 = nwg >> 3, r8 = nwg & 7;
  const int xcd = orig & 7, lp = orig >> 3;
  const int wg = (xcd < r8 ? xcd * (q8 + 1) : r8 * (q8 + 1) + (xcd - r8) * q8) + lp;
  const int bx = wg % nbx, by = wg / nbx;
  const long m0 = (long)by * 256, n0 = (long)bx * 128;

  const int tid = threadIdx.x, wid = tid >> 6, lane = tid & 63;
  const int wm = wid >> 1, wn = wid & 1;
  const int rl = lane & 15, g = lane >> 4;
  const int sw = ((g ^ ((rl >> 1) & 3)) << 3);

  int aoff[4], boff[4];
#pragma unroll
  for (int i = 0; i < 4; ++i) aoff[i] = (wm * 64 + i * 16 + rl) * 32 + sw;
#pragma unroll
  for (int j = 0; j < 4; ++j) boff[j] = (wn * 64 + j * 16 + rl) * 32 + sw;

  const int srow = tid >> 2;
  const int scolX = (((tid & 3) ^ ((srow >> 1) & 3)) << 3);

  f32x4 acc[4][4];
#pragma unroll
  for (int i = 0; i < 4; ++i)
#pragma unroll
    for (int j = 0; j < 4; ++j) acc[i][j] = (f32x4){0.f, 0.f, 0.f, 0.f};

#define STG128(H_) {                                                     \
    const u16* sa_ = Ab + (long)srow * lda + (H_) * 32 + scolX;          \
    u16* da_ = lds + (((H_) & 3) * 8192) + tid * 8;                      \
    gload_lds16(sa_, da_); gload_lds16(sa_ + (long)128 * lda, da_ + 4096); \
    gload_lds16(Bb + (long)srow * ldb + (H_) * 32 + scolX,               \
                lds + 32768 + (((H_) & 3) * 4096) + tid * 8); }
#define RD128(H_) {                                                      \
    const u16* aS_ = lds + ((H_) & 3) * 8192;                            \
    const u16* bS_ = lds + 32768 + ((H_) & 3) * 4096;                    \
    _Pragma("unroll") for (int i = 0; i < 4; ++i)                        \
      av[i] = *(const bf16x8*)(aS_ + aoff[i]);                           \
    _Pragma("unroll") for (int j = 0; j < 4; ++j)                        \
      bv[j] = *(const bf16x8*)(bS_ + boff[j]); }
#define MM128()                                                          \
  MM_PROLOG();                                                           \
  _Pragma("unroll") for (int i = 0; i < 4; ++i)                          \
    _Pragma("unroll") for (int j = 0; j < 4; ++j)                        \
      acc[i][j] = __builtin_amdgcn_mfma_f32_16x16x32_bf16(               \
          av[i], bv[j], acc[i][j], 0, 0, 0);                             \
  MM_EPILOG();

  const int NSEG = TWO_SEG ? 2 : 1;
#pragma unroll 1
  for (int seg = 0; seg < NSEG; ++seg) {
    const u16* Ab = ((seg == 0) ? A1 + (long)bz * sA1 : A2 + (long)bz * sA2);
    const u16* Bb = ((seg == 0) ? B1 + (long)bz * sB1 : B2 + (long)bz * sB2);
    const int lda = (seg == 0) ? lda1 : lda2;
    const int ldb = (seg == 0) ? ldb1 : ldb2;
    const int K   = (seg == 0) ? K1 : K2;
    Ab += m0 * lda;
    Bb += n0 * ldb;
    const int H = K >> 5;   // kk-halves; requires H >= 4

    bf16x8 av[4], bv[4];
    STG128(0); STG128(1); STG128(2);
    WAITV(6);
    CFENCE(); __builtin_amdgcn_s_barrier(); CFENCE();

#pragma unroll 1
    for (int h = 0; h < H - 3; ++h) {
      RD128(h); STG128(h + 3); WAITV(6); MM128();
    }
    RD128(H - 3); WAITV(3); MM128();
    RD128(H - 2); WAITV(0); MM128();
    RD128(H - 1); MM128();
  }
#undef STG128
#undef RD128
#undef MM128

  const int r0 = (lane >> 4) << 2;
  const int cL = lane & 15;
#pragma unroll
  for (int i = 0; i < 4; ++i) {
#pragma unroll
    for (int j = 0; j < 4; ++j) {
      const long row = m0 + wm * 64 + i * 16 + r0;
      const long col = n0 + wn * 64 + j * 16 + cL;
      float bvs = 0.f;
      if (HAS_BIAS) bvs = bias[col];
      if (OUT_BF16) {
        u16* Cp = (u16*)Cv + (long)bz * sC;
#pragma unroll
        for (int r = 0; r < 4; ++r)
          Cp[(row + r) * ldc + col] = f2bf(acc[i][j][r] * scale + bvs);
      } else {
        float* Cp = (float*)Cv + (long)bz * sC;
#pragma unroll
        for (int r = 0; r < 4; ++r)
          Cp[(row + r) * ldc + col] = acc[i][j][r] * scale + bvs;
      }
    }
  }
}

// ---------------------------------------------------------------------------
// Legacy 128x128 kernel for GEMM3 (K=128).
// ---------------------------------------------------------------------------
template<bool OUT_BF16, bool HAS_BIAS>
__global__ __launch_bounds__(256)
void gemm_bt(const u16* __restrict__ A, int lda, long sA,
             const u16* __restrict__ B, int ldb, long sB,
             void* __restrict__ Cv, int ldc, long sC,
             int K, float scale, const float* __restrict__ bias)
{
  __shared__ u16 As[128 * 64];
  __shared__ u16 Bs[128 * 64];
  const int bz   = blockIdx.z;
  const u16* Ap  = A + (long)bz * sA;
  const u16* Bp  = B + (long)bz * sB;
  const int tid  = threadIdx.x;
  const int wid  = tid >> 6;
  const int lane = tid & 63;
  const long m0  = (long)blockIdx.y * 128;
  const long n0  = (long)blockIdx.x * 128;
  const int lrow = lane >> 3;
  const int lk   = (lane & 7) << 3;
  const int wr   = wid >> 1, wc = wid & 1;

  f32x4 acc[4][4];
#pragma unroll
  for (int i = 0; i < 4; ++i)
#pragma unroll
    for (int j = 0; j < 4; ++j) acc[i][j] = (f32x4){0.f, 0.f, 0.f, 0.f};

  for (int k0 = 0; k0 < K; k0 += 64) {
#pragma unroll
    for (int c4 = 0; c4 < 4; ++c4) {
      const int chunk = (wid << 2) + c4;
      gload_lds16(Ap + (m0 + (chunk << 3) + lrow) * lda + k0 + lk, &As[chunk << 9]);
      gload_lds16(Bp + (n0 + (chunk << 3) + lrow) * ldb + k0 + lk, &Bs[chunk << 9]);
    }
    __syncthreads();
#pragma unroll
    for (int kk = 0; kk < 2; ++kk) {
      bf16x8 af[4], bfr[4];
      const int kof   = (kk << 5) + ((lane >> 4) << 3);
      const int rbase = lane & 15;
#pragma unroll
      for (int i = 0; i < 4; ++i)
        af[i] = *(const bf16x8*)&As[(((wr << 6) + (i << 4) + rbase) << 6) + kof];
#pragma unroll
      for (int j = 0; j < 4; ++j)
        bfr[j] = *(const bf16x8*)&Bs[(((wc << 6) + (j << 4) + rbase) << 6) + kof];
#pragma unroll
      for (int i = 0; i < 4; ++i)
#pragma unroll
        for (int j = 0; j < 4; ++j)
          acc[i][j] = __builtin_amdgcn_mfma_f32_16x16x32_bf16(af[i], bfr[j], acc[i][j], 0, 0, 0);
    }
    __syncthreads();
  }

  const int r0 = (lane >> 4) << 2;
  const int cL = lane & 15;
#pragma unroll
  for (int i = 0; i < 4; ++i) {
#pragma unroll
    for (int j = 0; j < 4; ++j) {
      const long row = m0 + (wr << 6) + (i << 4) + r0;
      const long col = n0 + (wc << 6) + (j << 4) + cL;
      float bv = 0.f;
      if (HAS_BIAS) bv = bias[col];
      if (OUT_BF16) {
        u16* Cp = (u16*)Cv + (long)bz * sC;
#pragma unroll
        for (int r = 0; r < 4; ++r)
          Cp[(row + r) * ldc + col] = f2bf(acc[i][j][r] * scale + bv);
      } else {
        float* Cp = (float*)Cv + (long)bz * sC;
#pragma unroll
        for (int r = 0; r < 4; ++r)
          Cp[(row + r) * ldc + col] = acc[i][j][r] * scale + bv;
      }
    }
  }
}

// Split-K (x8) variant for skinny GEMM4: atomicAdd f32 epilogue.
__global__ __launch_bounds__(256)
void gemm_bt_splitk(const u16* __restrict__ A, int lda, long sA,
                    const u16* __restrict__ B, int ldb, long sB,
                    float* __restrict__ C, int ldc, long sC,
                    int Kslice, float scale)
{
  __shared__ u16 As[128 * 64];
  __shared__ u16 Bs[128 * 64];
  const int ks = blockIdx.z & 7;
  const int bz = blockIdx.z >> 3;
  const u16* Ap  = A + (long)bz * sA + ks * Kslice;
  const u16* Bp  = B + (long)bz * sB + ks * Kslice;
  const int tid  = threadIdx.x;
  const int wid  = tid >> 6;
  const int lane = tid & 63;
  const long m0  = (long)blockIdx.y * 128;
  const long n0  = (long)blockIdx.x * 128;
  const int lrow = lane >> 3;
  const int lk   = (lane & 7) << 3;
  const int wr   = wid >> 1, wc = wid & 1;

  f32x4 acc[4][4];
#pragma unroll
  for (int i = 0; i < 4; ++i)
#pragma unroll
    for (int j = 0; j < 4; ++j) acc[i][j] = (f32x4){0.f, 0.f, 0.f, 0.f};

  for (int k0 = 0; k0 < Kslice; k0 += 64) {
#pragma unroll
    for (int c4 = 0; c4 < 4; ++c4) {
      const int chunk = (wid << 2) + c4;
      gload_lds16(Ap + (m0 + (chunk << 3) + lrow) * lda + k0 + lk, &As[chunk << 9]);
      gload_lds16(Bp + (n0 + (chunk << 3) + lrow) * ldb + k0 + lk, &Bs[chunk << 9]);
    }
    __syncthreads();
#pragma unroll
    for (int kk = 0; kk < 2; ++kk) {
      bf16x8 af[4], bfr[4];
      const int kof   = (kk << 5) + ((lane >> 4) << 3);
      const int rbase = lane & 15;
#pragma unroll
      for (int i = 0; i < 4; ++i)
        af[i] = *(const bf16x8*)&As[(((wr << 6) + (i << 4) + rbase) << 6) + kof];
#pragma unroll
      for (int j = 0; j < 4; ++j)
        bfr[j] = *(const bf16x8*)&Bs[(((wc << 6) + (j << 4) + rbase) << 6) + kof];
#pragma unroll
      for (int i = 0; i < 4; ++i)
#pragma unroll
        for (int j = 0; j < 4; ++j)
          acc[i][j] = __builtin_amdgcn_mfma_f32_16x16x32_bf16(af[i], bfr[j], acc[i][j], 0, 0, 0);
    }
    __syncthreads();
  }

  const int r0 = (lane >> 4) << 2;
  const int cL = lane & 15;
  float* Cp = C + (long)bz * sC;
#pragma unroll
  for (int i = 0; i < 4; ++i) {
#pragma unroll
    for (int j = 0; j < 4; ++j) {
      const long row = m0 + (wr << 6) + (i << 4) + r0;
      const long col = n0 + (wc << 6) + (j << 4) + cL;
#pragma unroll
      for (int r = 0; r < 4; ++r)
        atomicAdd(&Cp[(row + r) * ldc + col], acc[i][j][r] * scale);
    }
  }
}

// Row softmax over 2048 f32 -> bf16. One block (256 thr) per row.
__global__ __launch_bounds__(256)
void softmax_rows2048(const float* __restrict__ src, u16* __restrict__ dst) {
  const long row = blockIdx.x;
  const float4* s = (const float4*)(src + row * 2048);
  const int tid = threadIdx.x;
  float4 a = s[tid * 2], b = s[tid * 2 + 1];
  float m = fmaxf(fmaxf(fmaxf(a.x, a.y), fmaxf(a.z, a.w)),
                  fmaxf(fmaxf(b.x, b.y), fmaxf(b.z, b.w)));
#pragma unroll
  for (int o = 32; o > 0; o >>= 1) m = fmaxf(m, __shfl_xor(m, o));
  __shared__ float redm[4];
  __shared__ float reds[4];
  if ((tid & 63) == 0) redm[tid >> 6] = m;
  __syncthreads();
  m = fmaxf(fmaxf(redm[0], redm[1]), fmaxf(redm[2], redm[3]));
  float e[8];
  e[0] = __expf(a.x - m); e[1] = __expf(a.y - m); e[2] = __expf(a.z - m); e[3] = __expf(a.w - m);
  e[4] = __expf(b.x - m); e[5] = __expf(b.y - m); e[6] = __expf(b.z - m); e[7] = __expf(b.w - m);
  float sum = e[0] + e[1] + e[2] + e[3] + e[4] + e[5] + e[6] + e[7];
#pragma unroll
  for (int o = 32; o > 0; o >>= 1) sum += __shfl_xor(sum, o);
  if ((tid & 63) == 0) reds[tid >> 6] = sum;
  __syncthreads();
  sum = reds[0] + reds[1] + reds[2] + reds[3];
  const float inv = 1.f / sum;
  u16x4 o1 = { f2bf(e[0] * inv), f2bf(e[1] * inv), f2bf(e[2] * inv), f2bf(e[3] * inv) };
  u16x4 o2 = { f2bf(e[4] * inv), f2bf(e[5] * inv), f2bf(e[6] * inv), f2bf(e[7] * inv) };
  u16x4* d = (u16x4*)(dst + row * 2048);
  d[tid * 2]     = o1;
  d[tid * 2 + 1] = o2;
}

__global__ void transpose_f32_to_bf16(const float* __restrict__ src, u16* __restrict__ dst,
                                      int R, int C) {
  __shared__ float t[32][33];
  const int c0 = blockIdx.x * 32, r0 = blockIdx.y * 32;
  const int tx = threadIdx.x, ty = threadIdx.y;
#pragma unroll
  for (int i = 0; i < 4; ++i)
    t[ty + i * 8][tx] = src[(long)(r0 + ty + i * 8) * C + c0 + tx];
  __syncthreads();
#pragma unroll
  for (int i = 0; i < 4; ++i)
    dst[(long)(c0 + ty + i * 8) * R + r0 + tx] = f2bf(t[tx][ty + i * 8]);
}

__global__ void transpose_bf16_batched(const u16* __restrict__ src, int ss, long sbat,
                                       u16* __restrict__ dst, int ds, long dbat) {
  __shared__ u16 t[32][33];
  const u16* s = src + (long)blockIdx.z * sbat;
  u16* d = dst + (long)blockIdx.z * dbat;
  const int c0 = blockIdx.x * 32, r0 = blockIdx.y * 32;
  const int tx = threadIdx.x, ty = threadIdx.y;
#pragma unroll
  for (int i = 0; i < 4; ++i)
    t[ty + i * 8][tx] = s[(long)(r0 + ty + i * 8) * ss + c0 + tx];
  __syncthreads();
#pragma unroll
  for (int i = 0; i < 4; ++i)
    d[(long)(c0 + ty + i * 8) * ds + r0 + tx] = t[tx][ty + i * 8];
}

__global__ __launch_bounds__(256)
void convert_f32_to_bf16(const float* __restrict__ src, u16* __restrict__ dst, long n4) {
  long i = (long)blockIdx.x * 256 + threadIdx.x;
  if (i < n4) {
    float4 v = ((const float4*)src)[i];
    *(u16x4*)(dst + i * 4) = (u16x4){ f2bf(v.x), f2bf(v.y), f2bf(v.z), f2bf(v.w) };
  }
}

// camT = tanh(ctx * gate) * lw  (lw folded so GEMM2' uses plain SCALE)
__global__ __launch_bounds__(256)
void cam_tanh_kernel(const float* __restrict__ ctx, const float* __restrict__ gate,
                     const float* __restrict__ lw, u16* __restrict__ out, int n) {
  int i = blockIdx.x * 256 + threadIdx.x;
  if (i < n) {
    int d = i & 127;
    out[i] = f2bf(tanhf(ctx[i] * gate[d]) * lw[0]);
  }
}

__global__ __launch_bounds__(256)
void zero_f32(float* __restrict__ p, int n) {
  int i = blockIdx.x * 256 + threadIdx.x;
  if (i < n) p[i] = 0.f;
}

__global__ void calc_lw_kernel(const float* w0, const float* w1, float* lw) {
  *lw = 1.f / (1.f + __expf(-(w0[0] + 0.5f * w1[0])));
}

extern "C" void kernel_launch(void* const* d_in, const int* in_sizes, int n_in,
                              void* d_out, int out_size, void* d_ws, size_t ws_size,
                              hipStream_t stream) {
  const float* hs       = (const float*)d_in[0];
  const float* c_attn_w = (const float*)d_in[1];
  const float* c_attn_b = (const float*)d_in[2];
  const float* c_proj_w = (const float*)d_in[3];
  const float* c_proj_b = (const float*)d_in[4];
  const float* cam_gate = (const float*)d_in[5];
  const float* cam_w0   = (const float*)d_in[6];
  const float* cam_w1   = (const float*)d_in[7];
  float* out = (float*)d_out;

  char* w = (char*)d_ws;
  float* lw      = (float*)(w + 0);
  u16*   hs_b    = (u16*)(w + 256);                  // 16 MB (reused as baseA)
  u16*   waT_b   = (u16*)(w + 256 + 16777216UL);     // 24 MB
  u16*   wpT_b   = (u16*)(w + 256 + 41943040UL);     // 8 MB
  u16*   qkv_b   = (u16*)(w + 256 + 50331648UL);     // 48 MB
  u16*   vT_b    = (u16*)(w + 256 + 100663296UL);    // 16 MB
  float* scoresF = (float*)(w + 256 + 117440512UL);  // 32 MB (reused as ctxE bf16)
  float* camS    = (float*)(w + 256 + 150994944UL);  // 32 MB (reused as P bf16)
  float* ctxF    = (float*)(w + 256 + 184549376UL);  // 2 MB
  u16*   camT_b  = (u16*)(w + 256 + 186646528UL);    // 1 MB
  u16* baseA_b = hs_b;
  u16* P_b     = (u16*)camS;
  u16* ctxE_b  = (u16*)scoresF;

  dim3 b256(256);

  hipFuncSetAttribute((const void*)g256<true, true>,
                      hipFuncAttributeMaxDynamicSharedMemorySize, 131072);
  hipFuncSetAttribute((const void*)g128<false, false, true>,
                      hipFuncAttributeMaxDynamicSharedMemorySize, 98304);
  hipFuncSetAttribute((const void*)g128<true, false, false>,
                      hipFuncAttributeMaxDynamicSharedMemorySize, 98304);
  hipFuncSetAttribute((const void*)g128<false, true, false>,
                      hipFuncAttributeMaxDynamicSharedMemorySize, 98304);

  calc_lw_kernel<<<dim3(1), dim3(1), 0, stream>>>(cam_w0, cam_w1, lw);
  convert_f32_to_bf16<<<dim3(8192), b256, 0, stream>>>(hs, hs_b, 2097152L);
  transpose_f32_to_bf16<<<dim3(192, 64), dim3(32, 8), 0, stream>>>(c_attn_w, waT_b, 2048, 6144);
  transpose_f32_to_bf16<<<dim3(64, 64), dim3(32, 8), 0, stream>>>(c_proj_w, wpT_b, 2048, 2048);

  // GEMM1: qkv (4096x6144 bf16) = hs @ W_attn + b
  g256<true, true><<<dim3(384, 1, 1), dim3(512), 131072, stream>>>(
      hs_b, 2048, 0L, waT_b, 2048, 0L,
      qkv_b, 6144, 0L, 2048, 1.f, c_attn_b, 24);

  // V^T per batch (2048x2048 each)
  transpose_bf16_batched<<<dim3(64, 64, 2), dim3(32, 8), 0, stream>>>(
      qkv_b + 4096, 6144, 2048L * 6144, vT_b, 2048, 2048L * 2048);

  // GEMM3: camS = Q_cam @ K_cam^T * SCALE (K=128, f32)
  gemm_bt<false, false><<<dim3(16, 16, 2), b256, 0, stream>>>(
      qkv_b, 6144, 2048L * 6144, qkv_b + 2048, 6144, 2048L * 6144,
      camS, 2048, 2048L * 2048, 128, SCALE_QK, nullptr);

  // base_A = softmax(camS) -> bf16
  softmax_rows2048<<<dim3(4096), b256, 0, stream>>>(camS, baseA_b);

  // GEMM4: cam_ctx (2048x128 f32 per batch) = base_A @ V_cam — split-K x8
  zero_f32<<<dim3(2048), b256, 0, stream>>>(ctxF, 524288);
  gemm_bt_splitk<<<dim3(1, 16, 16), b256, 0, stream>>>(
      baseA_b, 2048, 2048L * 2048, vT_b, 2048, 2048L * 2048,
      ctxF, 128, 2048L * 128, 256, 1.f);

  // camT = tanh(cam_ctx * gate) * lw -> bf16
  cam_tanh_kernel<<<dim3(2048), b256, 0, stream>>>(ctxF, cam_gate, lw, camT_b, 524288);

  // GEMM2' (fused GEMM5): scores = SCALE*( Q@K^T + camT@K_cam^T ), f32
  g128<false, false, true><<<dim3(128, 1, 2), dim3(512), 98304, stream>>>(
      qkv_b, 6144, 2048L * 6144, qkv_b + 2048, 6144, 2048L * 6144, 2048,
      camT_b, 128, 2048L * 128, qkv_b + 2048, 6144, 2048L * 6144, 128,
      scoresF, 2048, 2048L * 2048, SCALE_QK, nullptr, 16);

  // P = softmax(scores) -> bf16
  softmax_rows2048<<<dim3(4096), b256, 0, stream>>>(scoresF, P_b);

  // GEMM6: context (bf16) = P @ V
  g128<true, false, false><<<dim3(128, 1, 2), dim3(512), 98304, stream>>>(
      P_b, 2048, 2048L * 2048, vT_b, 2048, 2048L * 2048, 2048,
      nullptr, 0, 0L, nullptr, 0, 0L, 0,
      ctxE_b, 2048, 2048L * 2048, 1.f, nullptr, 16);

  // GEMM7: out (f32) = context @ W_proj + b  (batches stacked: M=4096)
  g128<false, true, false><<<dim3(256, 1, 1), dim3(512), 98304, stream>>>(
      ctxE_b, 2048, 0L, wpT_b, 2048, 0L, 2048,
      nullptr, 0, 0L, nullptr, 0, 0L, 0,
      out, 2048, 0L, 1.f, c_proj_b, 16);
}

// Round 5
// 349.813 us; speedup vs baseline: 1.2403x; 1.0004x over previous
//
#include <hip/hip_runtime.h>
#include <hip/hip_bf16.h>

typedef unsigned short u16;
typedef __attribute__((ext_vector_type(8))) __bf16 bf16x8;
typedef __attribute__((ext_vector_type(4))) float f32x4;
typedef __attribute__((ext_vector_type(4))) unsigned short u16x4;

#define SCALE_QK 0.08838834764831845f

__device__ __forceinline__ u16 f2bf(float x) {
  union { float f; unsigned u; } v; v.f = x;
  unsigned r = v.u + 0x7fffu + ((v.u >> 16) & 1u);
  return (u16)(r >> 16);
}

__device__ __forceinline__ void gload_lds16(const u16* g, u16* l) {
  __builtin_amdgcn_global_load_lds(
      (const __attribute__((address_space(1))) unsigned*)g,
      (__attribute__((address_space(3))) unsigned*)l, 16, 0, 0);
}

#define CFENCE() asm volatile("" ::: "memory")
#define WAITV(N) asm volatile("s_waitcnt vmcnt(" #N ")" ::: "memory")

// Phase tail: barrier -> lgkm(0) -> sched_barrier -> prio1 MFMA cluster prio0 -> barrier
#define MM_PROLOG()                                                      \
  CFENCE(); __builtin_amdgcn_s_barrier();                                \
  asm volatile("s_waitcnt lgkmcnt(0)" ::: "memory");                     \
  __builtin_amdgcn_sched_barrier(0);                                     \
  __builtin_amdgcn_s_setprio(1);
#define MM_EPILOG()                                                      \
  __builtin_amdgcn_s_setprio(0);                                         \
  CFENCE(); __builtin_amdgcn_s_barrier(); CFENCE();

// ===========================================================================
// g256: 256x256 tile, BK=64, kk-half LDS slots (4-slot rotation per matrix),
// 4 phases/K-tile, unit staging (1 x 16KB half per phase, 6-unit lead),
// steady vmcnt(8) at p1/p3 only. 8 waves 2Mx4N. LDS 128 KiB.
// A slot h&3: [256][32] elems @ slot*8192 ; B region at elem 32768, same.
// Swizzle: 8-elem group g' = g ^ ((row>>1)&3); applied on global source and
// ds_read address; global_load_lds dest stays linear (rule #21).
// ===========================================================================
template<bool OUT_BF16, bool HAS_BIAS>
__global__ __launch_bounds__(512, 2)
void g256(const u16* __restrict__ A, int lda, long sA,
          const u16* __restrict__ B, int ldb, long sB,
          void* __restrict__ Cv, int ldc, long sC,
          int K, float scale, const float* __restrict__ bias, int nbx)
{
  extern __shared__ u16 lds[];
  const int bz = blockIdx.z;
  const int nwg = gridDim.x, orig = blockIdx.x;
  const int q8 = nwg >> 3, r8 = nwg & 7;
  const int xcd = orig & 7, lp = orig >> 3;
  const int wg = (xcd < r8 ? xcd * (q8 + 1) : r8 * (q8 + 1) + (xcd - r8) * q8) + lp;
  const int bx = wg % nbx, by = wg / nbx;
  const long m0 = (long)by * 256, n0 = (long)bx * 256;

  const int tid = threadIdx.x, wid = tid >> 6, lane = tid & 63;
  const int wm = wid >> 2, wn = wid & 3;
  const int rl = lane & 15, g = lane >> 4;
  const int sw = ((g ^ ((rl >> 1) & 3)) << 3);

  int aoff[8], boff[4];
#pragma unroll
  for (int i = 0; i < 8; ++i) aoff[i] = (wm * 128 + i * 16 + rl) * 32 + sw;
#pragma unroll
  for (int j = 0; j < 4; ++j) boff[j] = (wn * 64 + j * 16 + rl) * 32 + sw;

  const u16* Ab = A + (long)bz * sA + m0 * lda;
  const u16* Bb = B + (long)bz * sB + n0 * ldb;
  const int srow = tid >> 2;
  const int scolX = (((tid & 3) ^ ((srow >> 1) & 3)) << 3);

#define ST_A(H_) {                                                       \
    const u16* s_ = Ab + (long)srow * lda + (H_) * 32 + scolX;           \
    u16* d_ = lds + (((H_) & 3) * 8192) + tid * 8;                       \
    gload_lds16(s_, d_); gload_lds16(s_ + (long)128 * lda, d_ + 4096); }
#define ST_B(H_) {                                                       \
    const u16* s_ = Bb + (long)srow * ldb + (H_) * 32 + scolX;           \
    u16* d_ = lds + 32768 + (((H_) & 3) * 8192) + tid * 8;               \
    gload_lds16(s_, d_); gload_lds16(s_ + (long)128 * ldb, d_ + 4096); }
#define RDA(H_, IH) { const u16* aS_ = lds + ((H_) & 3) * 8192;          \
    _Pragma("unroll") for (int i = 0; i < 4; ++i)                        \
      av[i] = *(const bf16x8*)(aS_ + aoff[(IH) * 4 + i]); }
#define RDB(H_) { const u16* bS_ = lds + 32768 + ((H_) & 3) * 8192;      \
    _Pragma("unroll") for (int j = 0; j < 4; ++j)                        \
      bv[j] = *(const bf16x8*)(bS_ + boff[j]); }
#define MFMA16(IH)                                                       \
  MM_PROLOG();                                                           \
  _Pragma("unroll") for (int i = 0; i < 4; ++i)                          \
    _Pragma("unroll") for (int j = 0; j < 4; ++j)                        \
      acc[(IH) * 4 + i][j] = __builtin_amdgcn_mfma_f32_16x16x32_bf16(    \
          av[i], bv[j], acc[(IH) * 4 + i][j], 0, 0, 0);                  \
  MM_EPILOG();

  f32x4 acc[8][4];
#pragma unroll
  for (int i = 0; i < 8; ++i)
#pragma unroll
    for (int j = 0; j < 4; ++j) acc[i][j] = (f32x4){0.f, 0.f, 0.f, 0.f};

  const int NT = K >> 6;   // requires NT >= 2

  // prologue: units 0..5 = halves 0,1,2 of A and B
  ST_A(0); ST_B(0); ST_A(1); ST_B(1); ST_A(2); ST_B(2);
  WAITV(8);
  CFENCE(); __builtin_amdgcn_s_barrier(); CFENCE();

#pragma unroll 1
  for (int t = 0; t < NT - 2; ++t) {
    const int h0 = 2 * t, h1 = 2 * t + 1;
    bf16x8 av[4], bv[4];
    // p0
    RDA(h0, 0); RDB(h0); ST_A(h1 + 2); MFMA16(0);
    // p1
    RDA(h0, 1); ST_B(h1 + 2); WAITV(8); MFMA16(1);
    // p2
    RDA(h1, 0); RDB(h1); ST_A(h1 + 3); MFMA16(0);
    // p3
    RDA(h1, 1); ST_B(h1 + 3); WAITV(8); MFMA16(1);
  }
  { // tile NT-2: stage last halves at p0/p1 only
    const int h0 = 2 * NT - 4, h1 = 2 * NT - 3;
    bf16x8 av[4], bv[4];
    RDA(h0, 0); RDB(h0); ST_A(2 * NT - 1); MFMA16(0);
    RDA(h0, 1); ST_B(2 * NT - 1); WAITV(8); MFMA16(1);
    RDA(h1, 0); RDB(h1); MFMA16(0);
    RDA(h1, 1); WAITV(4); MFMA16(1);
  }
  { // tile NT-1: drain
    const int h0 = 2 * NT - 2, h1 = 2 * NT - 1;
    bf16x8 av[4], bv[4];
    RDA(h0, 0); RDB(h0); MFMA16(0);
    RDA(h0, 1); WAITV(0); MFMA16(1);
    RDA(h1, 0); RDB(h1); MFMA16(0);
    RDA(h1, 1); MFMA16(1);
  }
#undef ST_A
#undef ST_B
#undef RDA
#undef RDB
#undef MFMA16

  const int r0 = (lane >> 4) << 2;
  const int cL = lane & 15;
#pragma unroll
  for (int i = 0; i < 8; ++i) {
#pragma unroll
    for (int j = 0; j < 4; ++j) {
      const long row = m0 + wm * 128 + i * 16 + r0;
      const long col = n0 + wn * 64 + j * 16 + cL;
      float bvs = 0.f;
      if (HAS_BIAS) bvs = bias[col];
      if (OUT_BF16) {
        u16* Cp = (u16*)Cv + (long)bz * sC;
#pragma unroll
        for (int r = 0; r < 4; ++r)
          Cp[(row + r) * ldc + col] = f2bf(acc[i][j][r] * scale + bvs);
      } else {
        float* Cp = (float*)Cv + (long)bz * sC;
#pragma unroll
        for (int r = 0; r < 4; ++r)
          Cp[(row + r) * ldc + col] = acc[i][j][r] * scale + bvs;
      }
    }
  }
}

// ===========================================================================
// g128: 256x128 tile, BK=64, kk-half slots, ONE phase per kk-half
// (16 MFMA), 3 loads/half staged with 3-half lead -> steady vmcnt(6).
// 8 waves 4Mx2N, wave tile 64x64. LDS 96 KiB. Optional 2nd K-segment.
// ===========================================================================
template<bool OUT_BF16, bool HAS_BIAS, bool TWO_SEG>
__global__ __launch_bounds__(512, 2)
void g128(const u16* __restrict__ A1, int lda1, long sA1,
          const u16* __restrict__ B1, int ldb1, long sB1, int K1,
          const u16* __restrict__ A2, int lda2, long sA2,
          const u16* __restrict__ B2, int ldb2, long sB2, int K2,
          void* __restrict__ Cv, int ldc, long sC,
          float scale, const float* __restrict__ bias, int nbx)
{
  extern __shared__ u16 lds[];
  const int bz = blockIdx.z;
  const int nwg = gridDim.x, orig = blockIdx.x;
  const int q8 = nwg >> 3, r8 = nwg & 7;
  const int xcd = orig & 7, lp = orig >> 3;
  const int wg = (xcd < r8 ? xcd * (q8 + 1) : r8 * (q8 + 1) + (xcd - r8) * q8) + lp;
  const int bx = wg % nbx, by = wg / nbx;
  const long m0 = (long)by * 256, n0 = (long)bx * 128;

  const int tid = threadIdx.x, wid = tid >> 6, lane = tid & 63;
  const int wm = wid >> 1, wn = wid & 1;
  const int rl = lane & 15, g = lane >> 4;
  const int sw = ((g ^ ((rl >> 1) & 3)) << 3);

  int aoff[4], boff[4];
#pragma unroll
  for (int i = 0; i < 4; ++i) aoff[i] = (wm * 64 + i * 16 + rl) * 32 + sw;
#pragma unroll
  for (int j = 0; j < 4; ++j) boff[j] = (wn * 64 + j * 16 + rl) * 32 + sw;

  const int srow = tid >> 2;
  const int scolX = (((tid & 3) ^ ((srow >> 1) & 3)) << 3);

  f32x4 acc[4][4];
#pragma unroll
  for (int i = 0; i < 4; ++i)
#pragma unroll
    for (int j = 0; j < 4; ++j) acc[i][j] = (f32x4){0.f, 0.f, 0.f, 0.f};

#define STG128(H_) {                                                     \
    const u16* sa_ = Ab + (long)srow * lda + (H_) * 32 + scolX;          \
    u16* da_ = lds + (((H_) & 3) * 8192) + tid * 8;                      \
    gload_lds16(sa_, da_); gload_lds16(sa_ + (long)128 * lda, da_ + 4096); \
    gload_lds16(Bb + (long)srow * ldb + (H_) * 32 + scolX,               \
                lds + 32768 + (((H_) & 3) * 4096) + tid * 8); }
#define RD128(H_) {                                                      \
    const u16* aS_ = lds + ((H_) & 3) * 8192;                            \
    const u16* bS_ = lds + 32768 + ((H_) & 3) * 4096;                    \
    _Pragma("unroll") for (int i = 0; i < 4; ++i)                        \
      av[i] = *(const bf16x8*)(aS_ + aoff[i]);                           \
    _Pragma("unroll") for (int j = 0; j < 4; ++j)                        \
      bv[j] = *(const bf16x8*)(bS_ + boff[j]); }
#define MM128()                                                          \
  MM_PROLOG();                                                           \
  _Pragma("unroll") for (int i = 0; i < 4; ++i)                          \
    _Pragma("unroll") for (int j = 0; j < 4; ++j)                        \
      acc[i][j] = __builtin_amdgcn_mfma_f32_16x16x32_bf16(               \
          av[i], bv[j], acc[i][j], 0, 0, 0);                             \
  MM_EPILOG();

  const int NSEG = TWO_SEG ? 2 : 1;
#pragma unroll 1
  for (int seg = 0; seg < NSEG; ++seg) {
    const u16* Ab = ((seg == 0) ? A1 + (long)bz * sA1 : A2 + (long)bz * sA2);
    const u16* Bb = ((seg == 0) ? B1 + (long)bz * sB1 : B2 + (long)bz * sB2);
    const int lda = (seg == 0) ? lda1 : lda2;
    const int ldb = (seg == 0) ? ldb1 : ldb2;
    const int K   = (seg == 0) ? K1 : K2;
    Ab += m0 * lda;
    Bb += n0 * ldb;
    const int H = K >> 5;   // kk-halves; requires H >= 4

    bf16x8 av[4], bv[4];
    STG128(0); STG128(1); STG128(2);
    WAITV(6);
    CFENCE(); __builtin_amdgcn_s_barrier(); CFENCE();

#pragma unroll 1
    for (int h = 0; h < H - 3; ++h) {
      RD128(h); STG128(h + 3); WAITV(6); MM128();
    }
    RD128(H - 3); WAITV(3); MM128();
    RD128(H - 2); WAITV(0); MM128();
    RD128(H - 1); MM128();
  }
#undef STG128
#undef RD128
#undef MM128

  const int r0 = (lane >> 4) << 2;
  const int cL = lane & 15;
#pragma unroll
  for (int i = 0; i < 4; ++i) {
#pragma unroll
    for (int j = 0; j < 4; ++j) {
      const long row = m0 + wm * 64 + i * 16 + r0;
      const long col = n0 + wn * 64 + j * 16 + cL;
      float bvs = 0.f;
      if (HAS_BIAS) bvs = bias[col];
      if (OUT_BF16) {
        u16* Cp = (u16*)Cv + (long)bz * sC;
#pragma unroll
        for (int r = 0; r < 4; ++r)
          Cp[(row + r) * ldc + col] = f2bf(acc[i][j][r] * scale + bvs);
      } else {
        float* Cp = (float*)Cv + (long)bz * sC;
#pragma unroll
        for (int r = 0; r < 4; ++r)
          Cp[(row + r) * ldc + col] = acc[i][j][r] * scale + bvs;
      }
    }
  }
}

// ---------------------------------------------------------------------------
// Legacy 128x128 kernel for GEMM3 (K=128).
// ---------------------------------------------------------------------------
template<bool OUT_BF16, bool HAS_BIAS>
__global__ __launch_bounds__(256)
void gemm_bt(const u16* __restrict__ A, int lda, long sA,
             const u16* __restrict__ B, int ldb, long sB,
             void* __restrict__ Cv, int ldc, long sC,
             int K, float scale, const float* __restrict__ bias)
{
  __shared__ u16 As[128 * 64];
  __shared__ u16 Bs[128 * 64];
  const int bz   = blockIdx.z;
  const u16* Ap  = A + (long)bz * sA;
  const u16* Bp  = B + (long)bz * sB;
  const int tid  = threadIdx.x;
  const int wid  = tid >> 6;
  const int lane = tid & 63;
  const long m0  = (long)blockIdx.y * 128;
  const long n0  = (long)blockIdx.x * 128;
  const int lrow = lane >> 3;
  const int lk   = (lane & 7) << 3;
  const int wr   = wid >> 1, wc = wid & 1;

  f32x4 acc[4][4];
#pragma unroll
  for (int i = 0; i < 4; ++i)
#pragma unroll
    for (int j = 0; j < 4; ++j) acc[i][j] = (f32x4){0.f, 0.f, 0.f, 0.f};

  for (int k0 = 0; k0 < K; k0 += 64) {
#pragma unroll
    for (int c4 = 0; c4 < 4; ++c4) {
      const int chunk = (wid << 2) + c4;
      gload_lds16(Ap + (m0 + (chunk << 3) + lrow) * lda + k0 + lk, &As[chunk << 9]);
      gload_lds16(Bp + (n0 + (chunk << 3) + lrow) * ldb + k0 + lk, &Bs[chunk << 9]);
    }
    __syncthreads();
#pragma unroll
    for (int kk = 0; kk < 2; ++kk) {
      bf16x8 af[4], bfr[4];
      const int kof   = (kk << 5) + ((lane >> 4) << 3);
      const int rbase = lane & 15;
#pragma unroll
      for (int i = 0; i < 4; ++i)
        af[i] = *(const bf16x8*)&As[(((wr << 6) + (i << 4) + rbase) << 6) + kof];
#pragma unroll
      for (int j = 0; j < 4; ++j)
        bfr[j] = *(const bf16x8*)&Bs[(((wc << 6) + (j << 4) + rbase) << 6) + kof];
#pragma unroll
      for (int i = 0; i < 4; ++i)
#pragma unroll
        for (int j = 0; j < 4; ++j)
          acc[i][j] = __builtin_amdgcn_mfma_f32_16x16x32_bf16(af[i], bfr[j], acc[i][j], 0, 0, 0);
    }
    __syncthreads();
  }

  const int r0 = (lane >> 4) << 2;
  const int cL = lane & 15;
#pragma unroll
  for (int i = 0; i < 4; ++i) {
#pragma unroll
    for (int j = 0; j < 4; ++j) {
      const long row = m0 + (wr << 6) + (i << 4) + r0;
      const long col = n0 + (wc << 6) + (j << 4) + cL;
      float bv = 0.f;
      if (HAS_BIAS) bv = bias[col];
      if (OUT_BF16) {
        u16* Cp = (u16*)Cv + (long)bz * sC;
#pragma unroll
        for (int r = 0; r < 4; ++r)
          Cp[(row + r) * ldc + col] = f2bf(acc[i][j][r] * scale + bv);
      } else {
        float* Cp = (float*)Cv + (long)bz * sC;
#pragma unroll
        for (int r = 0; r < 4; ++r)
          Cp[(row + r) * ldc + col] = acc[i][j][r] * scale + bv;
      }
    }
  }
}

// Split-K (x8) variant for skinny GEMM4: atomicAdd f32 epilogue.
__global__ __launch_bounds__(256)
void gemm_bt_splitk(const u16* __restrict__ A, int lda, long sA,
                    const u16* __restrict__ B, int ldb, long sB,
                    float* __restrict__ C, int ldc, long sC,
                    int Kslice, float scale)
{
  __shared__ u16 As[128 * 64];
  __shared__ u16 Bs[128 * 64];
  const int ks = blockIdx.z & 7;
  const int bz = blockIdx.z >> 3;
  const u16* Ap  = A + (long)bz * sA + ks * Kslice;
  const u16* Bp  = B + (long)bz * sB + ks * Kslice;
  const int tid  = threadIdx.x;
  const int wid  = tid >> 6;
  const int lane = tid & 63;
  const long m0  = (long)blockIdx.y * 128;
  const long n0  = (long)blockIdx.x * 128;
  const int lrow = lane >> 3;
  const int lk   = (lane & 7) << 3;
  const int wr   = wid >> 1, wc = wid & 1;

  f32x4 acc[4][4];
#pragma unroll
  for (int i = 0; i < 4; ++i)
#pragma unroll
    for (int j = 0; j < 4; ++j) acc[i][j] = (f32x4){0.f, 0.f, 0.f, 0.f};

  for (int k0 = 0; k0 < Kslice; k0 += 64) {
#pragma unroll
    for (int c4 = 0; c4 < 4; ++c4) {
      const int chunk = (wid << 2) + c4;
      gload_lds16(Ap + (m0 + (chunk << 3) + lrow) * lda + k0 + lk, &As[chunk << 9]);
      gload_lds16(Bp + (n0 + (chunk << 3) + lrow) * ldb + k0 + lk, &Bs[chunk << 9]);
    }
    __syncthreads();
#pragma unroll
    for (int kk = 0; kk < 2; ++kk) {
      bf16x8 af[4], bfr[4];
      const int kof   = (kk << 5) + ((lane >> 4) << 3);
      const int rbase = lane & 15;
#pragma unroll
      for (int i = 0; i < 4; ++i)
        af[i] = *(const bf16x8*)&As[(((wr << 6) + (i << 4) + rbase) << 6) + kof];
#pragma unroll
      for (int j = 0; j < 4; ++j)
        bfr[j] = *(const bf16x8*)&Bs[(((wc << 6) + (j << 4) + rbase) << 6) + kof];
#pragma unroll
      for (int i = 0; i < 4; ++i)
#pragma unroll
        for (int j = 0; j < 4; ++j)
          acc[i][j] = __builtin_amdgcn_mfma_f32_16x16x32_bf16(af[i], bfr[j], acc[i][j], 0, 0, 0);
    }
    __syncthreads();
  }

  const int r0 = (lane >> 4) << 2;
  const int cL = lane & 15;
  float* Cp = C + (long)bz * sC;
#pragma unroll
  for (int i = 0; i < 4; ++i) {
#pragma unroll
    for (int j = 0; j < 4; ++j) {
      const long row = m0 + (wr << 6) + (i << 4) + r0;
      const long col = n0 + (wc << 6) + (j << 4) + cL;
#pragma unroll
      for (int r = 0; r < 4; ++r)
        atomicAdd(&Cp[(row + r) * ldc + col], acc[i][j][r] * scale);
    }
  }
}

// Row softmax over 2048 f32 -> bf16. One block (256 thr) per row.
__global__ __launch_bounds__(256)
void softmax_rows2048(const float* __restrict__ src, u16* __restrict__ dst) {
  const long row = blockIdx.x;
  const float4* s = (const float4*)(src + row * 2048);
  const int tid = threadIdx.x;
  float4 a = s[tid * 2], b = s[tid * 2 + 1];
  float m = fmaxf(fmaxf(fmaxf(a.x, a.y), fmaxf(a.z, a.w)),
                  fmaxf(fmaxf(b.x, b.y), fmaxf(b.z, b.w)));
#pragma unroll
  for (int o = 32; o > 0; o >>= 1) m = fmaxf(m, __shfl_xor(m, o));
  __shared__ float redm[4];
  __shared__ float reds[4];
  if ((tid & 63) == 0) redm[tid >> 6] = m;
  __syncthreads();
  m = fmaxf(fmaxf(redm[0], redm[1]), fmaxf(redm[2], redm[3]));
  float e[8];
  e[0] = __expf(a.x - m); e[1] = __expf(a.y - m); e[2] = __expf(a.z - m); e[3] = __expf(a.w - m);
  e[4] = __expf(b.x - m); e[5] = __expf(b.y - m); e[6] = __expf(b.z - m); e[7] = __expf(b.w - m);
  float sum = e[0] + e[1] + e[2] + e[3] + e[4] + e[5] + e[6] + e[7];
#pragma unroll
  for (int o = 32; o > 0; o >>= 1) sum += __shfl_xor(sum, o);
  if ((tid & 63) == 0) reds[tid >> 6] = sum;
  __syncthreads();
  sum = reds[0] + reds[1] + reds[2] + reds[3];
  const float inv = 1.f / sum;
  u16x4 o1 = { f2bf(e[0] * inv), f2bf(e[1] * inv), f2bf(e[2] * inv), f2bf(e[3] * inv) };
  u16x4 o2 = { f2bf(e[4] * inv), f2bf(e[5] * inv), f2bf(e[6] * inv), f2bf(e[7] * inv) };
  u16x4* d = (u16x4*)(dst + row * 2048);
  d[tid * 2]     = o1;
  d[tid * 2 + 1] = o2;
}

__global__ void transpose_f32_to_bf16(const float* __restrict__ src, u16* __restrict__ dst,
                                      int R, int C) {
  __shared__ float t[32][33];
  const int c0 = blockIdx.x * 32, r0 = blockIdx.y * 32;
  const int tx = threadIdx.x, ty = threadIdx.y;
#pragma unroll
  for (int i = 0; i < 4; ++i)
    t[ty + i * 8][tx] = src[(long)(r0 + ty + i * 8) * C + c0 + tx];
  __syncthreads();
#pragma unroll
  for (int i = 0; i < 4; ++i)
    dst[(long)(c0 + ty + i * 8) * R + r0 + tx] = f2bf(t[tx][ty + i * 8]);
}

__global__ void transpose_bf16_batched(const u16* __restrict__ src, int ss, long sbat,
                                       u16* __restrict__ dst, int ds, long dbat) {
  __shared__ u16 t[32][33];
  const u16* s = src + (long)blockIdx.z * sbat;
  u16* d = dst + (long)blockIdx.z * dbat;
  const int c0 = blockIdx.x * 32, r0 = blockIdx.y * 32;
  const int tx = threadIdx.x, ty = threadIdx.y;
#pragma unroll
  for (int i = 0; i < 4; ++i)
    t[ty + i * 8][tx] = s[(long)(r0 + ty + i * 8) * ss + c0 + tx];
  __syncthreads();
#pragma unroll
  for (int i = 0; i < 4; ++i)
    d[(long)(c0 + ty + i * 8) * ds + r0 + tx] = t[tx][ty + i * 8];
}

__global__ __launch_bounds__(256)
void convert_f32_to_bf16(const float* __restrict__ src, u16* __restrict__ dst, long n4) {
  long i = (long)blockIdx.x * 256 + threadIdx.x;
  if (i < n4) {
    float4 v = ((const float4*)src)[i];
    *(u16x4*)(dst + i * 4) = (u16x4){ f2bf(v.x), f2bf(v.y), f2bf(v.z), f2bf(v.w) };
  }
}

// camT = tanh(ctx * gate) * lw  (lw folded so GEMM2' uses plain SCALE)
__global__ __launch_bounds__(256)
void cam_tanh_kernel(const float* __restrict__ ctx, const float* __restrict__ gate,
                     const float* __restrict__ lw, u16* __restrict__ out, int n) {
  int i = blockIdx.x * 256 + threadIdx.x;
  if (i < n) {
    int d = i & 127;
    out[i] = f2bf(tanhf(ctx[i] * gate[d]) * lw[0]);
  }
}

__global__ __launch_bounds__(256)
void zero_f32(float* __restrict__ p, int n) {
  int i = blockIdx.x * 256 + threadIdx.x;
  if (i < n) p[i] = 0.f;
}

__global__ void calc_lw_kernel(const float* w0, const float* w1, float* lw) {
  *lw = 1.f / (1.f + __expf(-(w0[0] + 0.5f * w1[0])));
}

extern "C" void kernel_launch(void* const* d_in, const int* in_sizes, int n_in,
                              void* d_out, int out_size, void* d_ws, size_t ws_size,
                              hipStream_t stream) {
  const float* hs       = (const float*)d_in[0];
  const float* c_attn_w = (const float*)d_in[1];
  const float* c_attn_b = (const float*)d_in[2];
  const float* c_proj_w = (const float*)d_in[3];
  const float* c_proj_b = (const float*)d_in[4];
  const float* cam_gate = (const float*)d_in[5];
  const float* cam_w0   = (const float*)d_in[6];
  const float* cam_w1   = (const float*)d_in[7];
  float* out = (float*)d_out;

  char* w = (char*)d_ws;
  float* lw      = (float*)(w + 0);
  u16*   hs_b    = (u16*)(w + 256);                  // 16 MB (reused as baseA)
  u16*   waT_b   = (u16*)(w + 256 + 16777216UL);     // 24 MB
  u16*   wpT_b   = (u16*)(w + 256 + 41943040UL);     // 8 MB
  u16*   qkv_b   = (u16*)(w + 256 + 50331648UL);     // 48 MB
  u16*   vT_b    = (u16*)(w + 256 + 100663296UL);    // 16 MB
  float* scoresF = (float*)(w + 256 + 117440512UL);  // 32 MB (reused as ctxE bf16)
  float* camS    = (float*)(w + 256 + 150994944UL);  // 32 MB (reused as P bf16)
  float* ctxF    = (float*)(w + 256 + 184549376UL);  // 2 MB
  u16*   camT_b  = (u16*)(w + 256 + 186646528UL);    // 1 MB
  u16* baseA_b = hs_b;
  u16* P_b     = (u16*)camS;
  u16* ctxE_b  = (u16*)scoresF;

  dim3 b256(256);

  hipFuncSetAttribute((const void*)g256<true, true>,
                      hipFuncAttributeMaxDynamicSharedMemorySize, 131072);
  hipFuncSetAttribute((const void*)g128<false, false, true>,
                      hipFuncAttributeMaxDynamicSharedMemorySize, 98304);
  hipFuncSetAttribute((const void*)g128<true, false, false>,
                      hipFuncAttributeMaxDynamicSharedMemorySize, 98304);
  hipFuncSetAttribute((const void*)g128<false, true, false>,
                      hipFuncAttributeMaxDynamicSharedMemorySize, 98304);

  calc_lw_kernel<<<dim3(1), dim3(1), 0, stream>>>(cam_w0, cam_w1, lw);
  convert_f32_to_bf16<<<dim3(8192), b256, 0, stream>>>(hs, hs_b, 2097152L);
  transpose_f32_to_bf16<<<dim3(192, 64), dim3(32, 8), 0, stream>>>(c_attn_w, waT_b, 2048, 6144);
  transpose_f32_to_bf16<<<dim3(64, 64), dim3(32, 8), 0, stream>>>(c_proj_w, wpT_b, 2048, 2048);

  // GEMM1: qkv (4096x6144 bf16) = hs @ W_attn + b
  g256<true, true><<<dim3(384, 1, 1), dim3(512), 131072, stream>>>(
      hs_b, 2048, 0L, waT_b, 2048, 0L,
      qkv_b, 6144, 0L, 2048, 1.f, c_attn_b, 24);

  // V^T per batch (2048x2048 each)
  transpose_bf16_batched<<<dim3(64, 64, 2), dim3(32, 8), 0, stream>>>(
      qkv_b + 4096, 6144, 2048L * 6144, vT_b, 2048, 2048L * 2048);

  // GEMM3: camS = Q_cam @ K_cam^T * SCALE (K=128, f32)
  gemm_bt<false, false><<<dim3(16, 16, 2), b256, 0, stream>>>(
      qkv_b, 6144, 2048L * 6144, qkv_b + 2048, 6144, 2048L * 6144,
      camS, 2048, 2048L * 2048, 128, SCALE_QK, nullptr);

  // base_A = softmax(camS) -> bf16
  softmax_rows2048<<<dim3(4096), b256, 0, stream>>>(camS, baseA_b);

  // GEMM4: cam_ctx (2048x128 f32 per batch) = base_A @ V_cam — split-K x8
  zero_f32<<<dim3(2048), b256, 0, stream>>>(ctxF, 524288);
  gemm_bt_splitk<<<dim3(1, 16, 16), b256, 0, stream>>>(
      baseA_b, 2048, 2048L * 2048, vT_b, 2048, 2048L * 2048,
      ctxF, 128, 2048L * 128, 256, 1.f);

  // camT = tanh(cam_ctx * gate) * lw -> bf16
  cam_tanh_kernel<<<dim3(2048), b256, 0, stream>>>(ctxF, cam_gate, lw, camT_b, 524288);

  // GEMM2' (fused GEMM5): scores = SCALE*( Q@K^T + camT@K_cam^T ), f32
  g128<false, false, true><<<dim3(128, 1, 2), dim3(512), 98304, stream>>>(
      qkv_b, 6144, 2048L * 6144, qkv_b + 2048, 6144, 2048L * 6144, 2048,
      camT_b, 128, 2048L * 128, qkv_b + 2048, 6144, 2048L * 6144, 128,
      scoresF, 2048, 2048L * 2048, SCALE_QK, nullptr, 16);

  // P = softmax(scores) -> bf16
  softmax_rows2048<<<dim3(4096), b256, 0, stream>>>(scoresF, P_b);

  // GEMM6: context (bf16) = P @ V
  g128<true, false, false><<<dim3(128, 1, 2), dim3(512), 98304, stream>>>(
      P_b, 2048, 2048L * 2048, vT_b, 2048, 2048L * 2048, 2048,
      nullptr, 0, 0L, nullptr, 0, 0L, 0,
      ctxE_b, 2048, 2048L * 2048, 1.f, nullptr, 16);

  // GEMM7: out (f32) = context @ W_proj + b  (batches stacked: M=4096)
  g128<false, true, false><<<dim3(256, 1, 1), dim3(512), 98304, stream>>>(
      ctxE_b, 2048, 0L, wpT_b, 2048, 0L, 2048,
      nullptr, 0, 0L, nullptr, 0, 0L, 0,
      out, 2048, 0L, 1.f, c_proj_b, 16);
}

// Round 6
// 347.989 us; speedup vs baseline: 1.2468x; 1.0052x over previous
//
#include <hip/hip_runtime.h>
#include <hip/hip_bf16.h>

typedef unsigned short u16;
typedef __attribute__((ext_vector_type(8))) __bf16 bf16x8;
typedef __attribute__((ext_vector_type(4))) float f32x4;
typedef __attribute__((ext_vector_type(4))) unsigned short u16x4;

#define SCALE_QK 0.08838834764831845f

__device__ __forceinline__ u16 f2bf(float x) {
  union { float f; unsigned u; } v; v.f = x;
  unsigned r = v.u + 0x7fffu + ((v.u >> 16) & 1u);
  return (u16)(r >> 16);
}

__device__ __forceinline__ void gload_lds16(const u16* g, u16* l) {
  __builtin_amdgcn_global_load_lds(
      (const __attribute__((address_space(1))) unsigned*)g,
      (__attribute__((address_space(3))) unsigned*)l, 16, 0, 0);
}

#define CFENCE() asm volatile("" ::: "memory")
#define WAITV(N) asm volatile("s_waitcnt vmcnt(" #N ")" ::: "memory")

// ===========================================================================
// g128p: 256x128 tile, kk-half (K=32) pipeline units, 4-slot LDS rotation,
// ONE barrier per phase, register-double-buffered fragments (sets A/B).
// Phase body(k): WAITV(confirm slot k+1) ; barrier ; lgkm(0)+sched_barrier ;
//   setprio1 16xMFMA(regs k&1) setprio0 ; RD(k+1)->regs[(k+1)&1] ; STG(k+4).
// MFMA of slow waves overlaps ds_reads of fast waves (no trailing barrier;
// hazard ledger: STG(k+4) writes slot (k)&3, last read via RD(k) which is
// lgkm(0)-retired by every wave before barrier(k+1), and all waves are
// inside body(k) together). Steady vmcnt(6) = 2 slots x 3 loads in flight.
// 8 waves 4Mx2N (wave tile 64x64). LDS 96 KiB: A 4x[256][32] @0,
// B 4x[128][32] @32768 elems. Swizzle: 8-elem slot g' = g ^ ((row>>1)&3)
// on global source + ds_read addr; gload_lds dest linear (rule #21).
// Requires K%64==0 (H=K/32 even), K>=128. Optional 2nd K-segment.
// ===========================================================================
template<bool OUT_BF16, bool HAS_BIAS, bool TWO_SEG>
__global__ __launch_bounds__(512, 2)
void g128p(const u16* __restrict__ A1, int lda1, long sA1,
           const u16* __restrict__ B1, int ldb1, long sB1, int K1,
           const u16* __restrict__ A2, int lda2, long sA2,
           const u16* __restrict__ B2, int ldb2, long sB2, int K2,
           void* __restrict__ Cv, int ldc, long sC,
           float scale, const float* __restrict__ bias, int nbx)
{
  extern __shared__ u16 lds[];
  const int bz = blockIdx.z;
  const int nwg = gridDim.x, orig = blockIdx.x;
  const int q8 = nwg >> 3, r8 = nwg & 7;
  const int xcd = orig & 7, lp = orig >> 3;
  const int wg = (xcd < r8 ? xcd * (q8 + 1) : r8 * (q8 + 1) + (xcd - r8) * q8) + lp;
  const int bx = wg % nbx, by = wg / nbx;
  const long m0 = (long)by * 256, n0 = (long)bx * 128;

  const int tid = threadIdx.x, wid = tid >> 6, lane = tid & 63;
  const int wm = wid >> 1, wn = wid & 1;
  const int rl = lane & 15, g = lane >> 4;
  const int sw = ((g ^ ((rl >> 1) & 3)) << 3);

  int aoff[4], boff[4];
#pragma unroll
  for (int i = 0; i < 4; ++i) aoff[i] = (wm * 64 + i * 16 + rl) * 32 + sw;
#pragma unroll
  for (int j = 0; j < 4; ++j) boff[j] = (wn * 64 + j * 16 + rl) * 32 + sw;

  const int srow = tid >> 2;
  const int scolX = (((tid & 3) ^ ((srow >> 1) & 3)) << 3);

  f32x4 acc[4][4];
#pragma unroll
  for (int i = 0; i < 4; ++i)
#pragma unroll
    for (int j = 0; j < 4; ++j) acc[i][j] = (f32x4){0.f, 0.f, 0.f, 0.f};

  bf16x8 avA[4], bvA[4], avB[4], bvB[4];

#define STG(H_) {                                                        \
    const int h_ = (H_);                                                 \
    const u16* sa_ = Ab + (long)srow * lda + h_ * 32 + scolX;            \
    u16* da_ = lds + ((h_ & 3) * 8192) + tid * 8;                        \
    gload_lds16(sa_, da_);                                               \
    gload_lds16(sa_ + (long)128 * lda, da_ + 4096);                      \
    gload_lds16(Bb + (long)srow * ldb + h_ * 32 + scolX,                 \
                lds + 32768 + ((h_ & 3) * 4096) + tid * 8); }
#define RD(H_, AV, BV) {                                                 \
    const u16* aS_ = lds + (((H_) & 3) * 8192);                          \
    const u16* bS_ = lds + 32768 + (((H_) & 3) * 4096);                  \
    _Pragma("unroll") for (int i_ = 0; i_ < 4; ++i_)                     \
      AV[i_] = *(const bf16x8*)(aS_ + aoff[i_]);                         \
    _Pragma("unroll") for (int j_ = 0; j_ < 4; ++j_)                     \
      BV[j_] = *(const bf16x8*)(bS_ + boff[j_]); }
#define BODY(K_, CAV, CBV, NAV, NBV, W_STMT, DO_RD, DO_ST)               \
    W_STMT;                                                              \
    CFENCE(); __builtin_amdgcn_s_barrier(); CFENCE();                    \
    asm volatile("s_waitcnt lgkmcnt(0)" ::: "memory");                   \
    __builtin_amdgcn_sched_barrier(0);                                   \
    __builtin_amdgcn_s_setprio(1);                                       \
    _Pragma("unroll") for (int i_ = 0; i_ < 4; ++i_)                     \
      _Pragma("unroll") for (int j_ = 0; j_ < 4; ++j_)                   \
        acc[i_][j_] = __builtin_amdgcn_mfma_f32_16x16x32_bf16(           \
            CAV[i_], CBV[j_], acc[i_][j_], 0, 0, 0);                     \
    __builtin_amdgcn_s_setprio(0);                                       \
    if (DO_RD) { RD((K_) + 1, NAV, NBV); }                               \
    if (DO_ST) { STG((K_) + 4); }                                        \
    CFENCE();

  const int NSEG = TWO_SEG ? 2 : 1;
#pragma unroll 1
  for (int seg = 0; seg < NSEG; ++seg) {
    const int lda = (seg == 0) ? lda1 : lda2;
    const int ldb = (seg == 0) ? ldb1 : ldb2;
    const int K   = (seg == 0) ? K1 : K2;
    const u16* Ab = ((seg == 0) ? A1 + (long)bz * sA1 : A2 + (long)bz * sA2) + m0 * (long)lda;
    const u16* Bb = ((seg == 0) ? B1 + (long)bz * sB1 : B2 + (long)bz * sB2) + n0 * (long)ldb;
    const int H = K >> 5;   // kk-halves; H even, >= 4

    // prologue: stage slots 0..2 (9 loads), confirm slot 0, read frag 0, stage 3
    STG(0); STG(1); STG(2);
    WAITV(6);
    CFENCE(); __builtin_amdgcn_s_barrier(); CFENCE();
    RD(0, avA, bvA);
    STG(3);
    CFENCE();

#pragma unroll 1
    for (int k = 0; k + 5 < H; k += 2) {
      BODY(k,     avA, bvA, avB, bvB, WAITV(6), true, true);
      BODY(k + 1, avB, bvB, avA, bvA, WAITV(6), true, true);
    }
    BODY(H - 4, avA, bvA, avB, bvB, WAITV(6), true,  false);
    BODY(H - 3, avB, bvB, avA, bvA, WAITV(3), true,  false);
    BODY(H - 2, avA, bvA, avB, bvB, WAITV(0), true,  false);
    BODY(H - 1, avB, bvB, avA, bvA, (void)0,  false, false);
  }
#undef STG
#undef RD
#undef BODY

  const int r0 = (lane >> 4) << 2;
  const int cL = lane & 15;
#pragma unroll
  for (int i = 0; i < 4; ++i) {
#pragma unroll
    for (int j = 0; j < 4; ++j) {
      const long row = m0 + wm * 64 + i * 16 + r0;
      const long col = n0 + wn * 64 + j * 16 + cL;
      float bvs = 0.f;
      if (HAS_BIAS) bvs = bias[col];
      if (OUT_BF16) {
        u16* Cp = (u16*)Cv + (long)bz * sC;
#pragma unroll
        for (int r = 0; r < 4; ++r)
          Cp[(row + r) * ldc + col] = f2bf(acc[i][j][r] * scale + bvs);
      } else {
        float* Cp = (float*)Cv + (long)bz * sC;
#pragma unroll
        for (int r = 0; r < 4; ++r)
          Cp[(row + r) * ldc + col] = acc[i][j][r] * scale + bvs;
      }
    }
  }
}

// ---------------------------------------------------------------------------
// Legacy 128x128 kernel for GEMM3 (K=128).
// ---------------------------------------------------------------------------
template<bool OUT_BF16, bool HAS_BIAS>
__global__ __launch_bounds__(256)
void gemm_bt(const u16* __restrict__ A, int lda, long sA,
             const u16* __restrict__ B, int ldb, long sB,
             void* __restrict__ Cv, int ldc, long sC,
             int K, float scale, const float* __restrict__ bias)
{
  __shared__ u16 As[128 * 64];
  __shared__ u16 Bs[128 * 64];
  const int bz   = blockIdx.z;
  const u16* Ap  = A + (long)bz * sA;
  const u16* Bp  = B + (long)bz * sB;
  const int tid  = threadIdx.x;
  const int wid  = tid >> 6;
  const int lane = tid & 63;
  const long m0  = (long)blockIdx.y * 128;
  const long n0  = (long)blockIdx.x * 128;
  const int lrow = lane >> 3;
  const int lk   = (lane & 7) << 3;
  const int wr   = wid >> 1, wc = wid & 1;

  f32x4 acc[4][4];
#pragma unroll
  for (int i = 0; i < 4; ++i)
#pragma unroll
    for (int j = 0; j < 4; ++j) acc[i][j] = (f32x4){0.f, 0.f, 0.f, 0.f};

  for (int k0 = 0; k0 < K; k0 += 64) {
#pragma unroll
    for (int c4 = 0; c4 < 4; ++c4) {
      const int chunk = (wid << 2) + c4;
      gload_lds16(Ap + (m0 + (chunk << 3) + lrow) * lda + k0 + lk, &As[chunk << 9]);
      gload_lds16(Bp + (n0 + (chunk << 3) + lrow) * ldb + k0 + lk, &Bs[chunk << 9]);
    }
    __syncthreads();
#pragma unroll
    for (int kk = 0; kk < 2; ++kk) {
      bf16x8 af[4], bfr[4];
      const int kof   = (kk << 5) + ((lane >> 4) << 3);
      const int rbase = lane & 15;
#pragma unroll
      for (int i = 0; i < 4; ++i)
        af[i] = *(const bf16x8*)&As[(((wr << 6) + (i << 4) + rbase) << 6) + kof];
#pragma unroll
      for (int j = 0; j < 4; ++j)
        bfr[j] = *(const bf16x8*)&Bs[(((wc << 6) + (j << 4) + rbase) << 6) + kof];
#pragma unroll
      for (int i = 0; i < 4; ++i)
#pragma unroll
        for (int j = 0; j < 4; ++j)
          acc[i][j] = __builtin_amdgcn_mfma_f32_16x16x32_bf16(af[i], bfr[j], acc[i][j], 0, 0, 0);
    }
    __syncthreads();
  }

  const int r0 = (lane >> 4) << 2;
  const int cL = lane & 15;
#pragma unroll
  for (int i = 0; i < 4; ++i) {
#pragma unroll
    for (int j = 0; j < 4; ++j) {
      const long row = m0 + (wr << 6) + (i << 4) + r0;
      const long col = n0 + (wc << 6) + (j << 4) + cL;
      float bv = 0.f;
      if (HAS_BIAS) bv = bias[col];
      if (OUT_BF16) {
        u16* Cp = (u16*)Cv + (long)bz * sC;
#pragma unroll
        for (int r = 0; r < 4; ++r)
          Cp[(row + r) * ldc + col] = f2bf(acc[i][j][r] * scale + bv);
      } else {
        float* Cp = (float*)Cv + (long)bz * sC;
#pragma unroll
        for (int r = 0; r < 4; ++r)
          Cp[(row + r) * ldc + col] = acc[i][j][r] * scale + bv;
      }
    }
  }
}

// Split-K (x8) variant for skinny GEMM4: atomicAdd f32 epilogue.
__global__ __launch_bounds__(256)
void gemm_bt_splitk(const u16* __restrict__ A, int lda, long sA,
                    const u16* __restrict__ B, int ldb, long sB,
                    float* __restrict__ C, int ldc, long sC,
                    int Kslice, float scale)
{
  __shared__ u16 As[128 * 64];
  __shared__ u16 Bs[128 * 64];
  const int ks = blockIdx.z & 7;
  const int bz = blockIdx.z >> 3;
  const u16* Ap  = A + (long)bz * sA + ks * Kslice;
  const u16* Bp  = B + (long)bz * sB + ks * Kslice;
  const int tid  = threadIdx.x;
  const int wid  = tid >> 6;
  const int lane = tid & 63;
  const long m0  = (long)blockIdx.y * 128;
  const long n0  = (long)blockIdx.x * 128;
  const int lrow = lane >> 3;
  const int lk   = (lane & 7) << 3;
  const int wr   = wid >> 1, wc = wid & 1;

  f32x4 acc[4][4];
#pragma unroll
  for (int i = 0; i < 4; ++i)
#pragma unroll
    for (int j = 0; j < 4; ++j) acc[i][j] = (f32x4){0.f, 0.f, 0.f, 0.f};

  for (int k0 = 0; k0 < Kslice; k0 += 64) {
#pragma unroll
    for (int c4 = 0; c4 < 4; ++c4) {
      const int chunk = (wid << 2) + c4;
      gload_lds16(Ap + (m0 + (chunk << 3) + lrow) * lda + k0 + lk, &As[chunk << 9]);
      gload_lds16(Bp + (n0 + (chunk << 3) + lrow) * ldb + k0 + lk, &Bs[chunk << 9]);
    }
    __syncthreads();
#pragma unroll
    for (int kk = 0; kk < 2; ++kk) {
      bf16x8 af[4], bfr[4];
      const int kof   = (kk << 5) + ((lane >> 4) << 3);
      const int rbase = lane & 15;
#pragma unroll
      for (int i = 0; i < 4; ++i)
        af[i] = *(const bf16x8*)&As[(((wr << 6) + (i << 4) + rbase) << 6) + kof];
#pragma unroll
      for (int j = 0; j < 4; ++j)
        bfr[j] = *(const bf16x8*)&Bs[(((wc << 6) + (j << 4) + rbase) << 6) + kof];
#pragma unroll
      for (int i = 0; i < 4; ++i)
#pragma unroll
        for (int j = 0; j < 4; ++j)
          acc[i][j] = __builtin_amdgcn_mfma_f32_16x16x32_bf16(af[i], bfr[j], acc[i][j], 0, 0, 0);
    }
    __syncthreads();
  }

  const int r0 = (lane >> 4) << 2;
  const int cL = lane & 15;
  float* Cp = C + (long)bz * sC;
#pragma unroll
  for (int i = 0; i < 4; ++i) {
#pragma unroll
    for (int j = 0; j < 4; ++j) {
      const long row = m0 + (wr << 6) + (i << 4) + r0;
      const long col = n0 + (wc << 6) + (j << 4) + cL;
#pragma unroll
      for (int r = 0; r < 4; ++r)
        atomicAdd(&Cp[(row + r) * ldc + col], acc[i][j][r] * scale);
    }
  }
}

// Row softmax over 2048 f32 -> bf16. One block (256 thr) per row.
__global__ __launch_bounds__(256)
void softmax_rows2048(const float* __restrict__ src, u16* __restrict__ dst) {
  const long row = blockIdx.x;
  const float4* s = (const float4*)(src + row * 2048);
  const int tid = threadIdx.x;
  float4 a = s[tid * 2], b = s[tid * 2 + 1];
  float m = fmaxf(fmaxf(fmaxf(a.x, a.y), fmaxf(a.z, a.w)),
                  fmaxf(fmaxf(b.x, b.y), fmaxf(b.z, b.w)));
#pragma unroll
  for (int o = 32; o > 0; o >>= 1) m = fmaxf(m, __shfl_xor(m, o));
  __shared__ float redm[4];
  __shared__ float reds[4];
  if ((tid & 63) == 0) redm[tid >> 6] = m;
  __syncthreads();
  m = fmaxf(fmaxf(redm[0], redm[1]), fmaxf(redm[2], redm[3]));
  float e[8];
  e[0] = __expf(a.x - m); e[1] = __expf(a.y - m); e[2] = __expf(a.z - m); e[3] = __expf(a.w - m);
  e[4] = __expf(b.x - m); e[5] = __expf(b.y - m); e[6] = __expf(b.z - m); e[7] = __expf(b.w - m);
  float sum = e[0] + e[1] + e[2] + e[3] + e[4] + e[5] + e[6] + e[7];
#pragma unroll
  for (int o = 32; o > 0; o >>= 1) sum += __shfl_xor(sum, o);
  if ((tid & 63) == 0) reds[tid >> 6] = sum;
  __syncthreads();
  sum = reds[0] + reds[1] + reds[2] + reds[3];
  const float inv = 1.f / sum;
  u16x4 o1 = { f2bf(e[0] * inv), f2bf(e[1] * inv), f2bf(e[2] * inv), f2bf(e[3] * inv) };
  u16x4 o2 = { f2bf(e[4] * inv), f2bf(e[5] * inv), f2bf(e[6] * inv), f2bf(e[7] * inv) };
  u16x4* d = (u16x4*)(dst + row * 2048);
  d[tid * 2]     = o1;
  d[tid * 2 + 1] = o2;
}

__global__ void transpose_f32_to_bf16(const float* __restrict__ src, u16* __restrict__ dst,
                                      int R, int C) {
  __shared__ float t[32][33];
  const int c0 = blockIdx.x * 32, r0 = blockIdx.y * 32;
  const int tx = threadIdx.x, ty = threadIdx.y;
#pragma unroll
  for (int i = 0; i < 4; ++i)
    t[ty + i * 8][tx] = src[(long)(r0 + ty + i * 8) * C + c0 + tx];
  __syncthreads();
#pragma unroll
  for (int i = 0; i < 4; ++i)
    dst[(long)(c0 + ty + i * 8) * R + r0 + tx] = f2bf(t[tx][ty + i * 8]);
}

__global__ void transpose_bf16_batched(const u16* __restrict__ src, int ss, long sbat,
                                       u16* __restrict__ dst, int ds, long dbat) {
  __shared__ u16 t[32][33];
  const u16* s = src + (long)blockIdx.z * sbat;
  u16* d = dst + (long)blockIdx.z * dbat;
  const int c0 = blockIdx.x * 32, r0 = blockIdx.y * 32;
  const int tx = threadIdx.x, ty = threadIdx.y;
#pragma unroll
  for (int i = 0; i < 4; ++i)
    t[ty + i * 8][tx] = s[(long)(r0 + ty + i * 8) * ss + c0 + tx];
  __syncthreads();
#pragma unroll
  for (int i = 0; i < 4; ++i)
    d[(long)(c0 + ty + i * 8) * ds + r0 + tx] = t[tx][ty + i * 8];
}

__global__ __launch_bounds__(256)
void convert_f32_to_bf16(const float* __restrict__ src, u16* __restrict__ dst, long n4) {
  long i = (long)blockIdx.x * 256 + threadIdx.x;
  if (i < n4) {
    float4 v = ((const float4*)src)[i];
    *(u16x4*)(dst + i * 4) = (u16x4){ f2bf(v.x), f2bf(v.y), f2bf(v.z), f2bf(v.w) };
  }
}

// camT = tanh(ctx * gate) * lw  (lw folded so GEMM2' uses plain SCALE)
__global__ __launch_bounds__(256)
void cam_tanh_kernel(const float* __restrict__ ctx, const float* __restrict__ gate,
                     const float* __restrict__ lw, u16* __restrict__ out, int n) {
  int i = blockIdx.x * 256 + threadIdx.x;
  if (i < n) {
    int d = i & 127;
    out[i] = f2bf(tanhf(ctx[i] * gate[d]) * lw[0]);
  }
}

__global__ __launch_bounds__(256)
void zero_f32(float* __restrict__ p, int n) {
  int i = blockIdx.x * 256 + threadIdx.x;
  if (i < n) p[i] = 0.f;
}

__global__ void calc_lw_kernel(const float* w0, const float* w1, float* lw) {
  *lw = 1.f / (1.f + __expf(-(w0[0] + 0.5f * w1[0])));
}

extern "C" void kernel_launch(void* const* d_in, const int* in_sizes, int n_in,
                              void* d_out, int out_size, void* d_ws, size_t ws_size,
                              hipStream_t stream) {
  const float* hs       = (const float*)d_in[0];
  const float* c_attn_w = (const float*)d_in[1];
  const float* c_attn_b = (const float*)d_in[2];
  const float* c_proj_w = (const float*)d_in[3];
  const float* c_proj_b = (const float*)d_in[4];
  const float* cam_gate = (const float*)d_in[5];
  const float* cam_w0   = (const float*)d_in[6];
  const float* cam_w1   = (const float*)d_in[7];
  float* out = (float*)d_out;

  char* w = (char*)d_ws;
  float* lw      = (float*)(w + 0);
  u16*   hs_b    = (u16*)(w + 256);                  // 16 MB (reused as baseA)
  u16*   waT_b   = (u16*)(w + 256 + 16777216UL);     // 24 MB
  u16*   wpT_b   = (u16*)(w + 256 + 41943040UL);     // 8 MB
  u16*   qkv_b   = (u16*)(w + 256 + 50331648UL);     // 48 MB
  u16*   vT_b    = (u16*)(w + 256 + 100663296UL);    // 16 MB
  float* scoresF = (float*)(w + 256 + 117440512UL);  // 32 MB (reused as ctxE bf16)
  float* camS    = (float*)(w + 256 + 150994944UL);  // 32 MB (reused as P bf16)
  float* ctxF    = (float*)(w + 256 + 184549376UL);  // 2 MB
  u16*   camT_b  = (u16*)(w + 256 + 186646528UL);    // 1 MB
  u16* baseA_b = hs_b;
  u16* P_b     = (u16*)camS;
  u16* ctxE_b  = (u16*)scoresF;

  dim3 b256(256);

  hipFuncSetAttribute((const void*)g128p<true, true, false>,
                      hipFuncAttributeMaxDynamicSharedMemorySize, 98304);
  hipFuncSetAttribute((const void*)g128p<false, false, true>,
                      hipFuncAttributeMaxDynamicSharedMemorySize, 98304);
  hipFuncSetAttribute((const void*)g128p<true, false, false>,
                      hipFuncAttributeMaxDynamicSharedMemorySize, 98304);
  hipFuncSetAttribute((const void*)g128p<false, true, false>,
                      hipFuncAttributeMaxDynamicSharedMemorySize, 98304);

  calc_lw_kernel<<<dim3(1), dim3(1), 0, stream>>>(cam_w0, cam_w1, lw);
  convert_f32_to_bf16<<<dim3(8192), b256, 0, stream>>>(hs, hs_b, 2097152L);
  transpose_f32_to_bf16<<<dim3(192, 64), dim3(32, 8), 0, stream>>>(c_attn_w, waT_b, 2048, 6144);
  transpose_f32_to_bf16<<<dim3(64, 64), dim3(32, 8), 0, stream>>>(c_proj_w, wpT_b, 2048, 2048);

  // GEMM1: qkv (4096x6144 bf16) = hs @ W_attn + b — 768 blocks = 3 full rounds
  g128p<true, true, false><<<dim3(768, 1, 1), dim3(512), 98304, stream>>>(
      hs_b, 2048, 0L, waT_b, 2048, 0L, 2048,
      nullptr, 0, 0L, nullptr, 0, 0L, 0,
      qkv_b, 6144, 0L, 1.f, c_attn_b, 48);

  // V^T per batch (2048x2048 each)
  transpose_bf16_batched<<<dim3(64, 64, 2), dim3(32, 8), 0, stream>>>(
      qkv_b + 4096, 6144, 2048L * 6144, vT_b, 2048, 2048L * 2048);

  // GEMM3: camS = Q_cam @ K_cam^T * SCALE (K=128, f32)
  gemm_bt<false, false><<<dim3(16, 16, 2), b256, 0, stream>>>(
      qkv_b, 6144, 2048L * 6144, qkv_b + 2048, 6144, 2048L * 6144,
      camS, 2048, 2048L * 2048, 128, SCALE_QK, nullptr);

  // base_A = softmax(camS) -> bf16
  softmax_rows2048<<<dim3(4096), b256, 0, stream>>>(camS, baseA_b);

  // GEMM4: cam_ctx (2048x128 f32 per batch) = base_A @ V_cam — split-K x8
  zero_f32<<<dim3(2048), b256, 0, stream>>>(ctxF, 524288);
  gemm_bt_splitk<<<dim3(1, 16, 16), b256, 0, stream>>>(
      baseA_b, 2048, 2048L * 2048, vT_b, 2048, 2048L * 2048,
      ctxF, 128, 2048L * 128, 256, 1.f);

  // camT = tanh(cam_ctx * gate) * lw -> bf16
  cam_tanh_kernel<<<dim3(2048), b256, 0, stream>>>(ctxF, cam_gate, lw, camT_b, 524288);

  // GEMM2' (fused GEMM5): scores = SCALE*( Q@K^T + camT@K_cam^T ), f32
  g128p<false, false, true><<<dim3(128, 1, 2), dim3(512), 98304, stream>>>(
      qkv_b, 6144, 2048L * 6144, qkv_b + 2048, 6144, 2048L * 6144, 2048,
      camT_b, 128, 2048L * 128, qkv_b + 2048, 6144, 2048L * 6144, 128,
      scoresF, 2048, 2048L * 2048, SCALE_QK, nullptr, 16);

  // P = softmax(scores) -> bf16
  softmax_rows2048<<<dim3(4096), b256, 0, stream>>>(scoresF, P_b);

  // GEMM6: context (bf16) = P @ V
  g128p<true, false, false><<<dim3(128, 1, 2), dim3(512), 98304, stream>>>(
      P_b, 2048, 2048L * 2048, vT_b, 2048, 2048L * 2048, 2048,
      nullptr, 0, 0L, nullptr, 0, 0L, 0,
      ctxE_b, 2048, 2048L * 2048, 1.f, nullptr, 16);

  // GEMM7: out (f32) = context @ W_proj + b  (batches stacked: M=4096)
  g128p<false, true, false><<<dim3(256, 1, 1), dim3(512), 98304, stream>>>(
      ctxE_b, 2048, 0L, wpT_b, 2048, 0L, 2048,
      nullptr, 0, 0L, nullptr, 0, 0L, 0,
      out, 2048, 0L, 1.f, c_proj_b, 16);
}